// Round 9
// baseline (235.460 us; speedup 1.0000x reference)
//
#include <hip/hip_runtime.h>

#define BT 4096      // B*T
#define Dd 1024
#define Tt 2048

typedef __attribute__((ext_vector_type(8))) short bf16x8;
typedef __attribute__((ext_vector_type(4))) float f32x4;
typedef __attribute__((ext_vector_type(4))) unsigned u32x4;

__device__ __forceinline__ short f2bf(float f) {
  unsigned u = __builtin_bit_cast(unsigned, f);
  u = (u + 0x7FFFu + ((u >> 16) & 1u)) >> 16;
  return (short)u;
}
__device__ __forceinline__ float bf2f(short s) {
  unsigned u = ((unsigned)(unsigned short)s) << 16;
  return __builtin_bit_cast(float, u);
}
__device__ __forceinline__ unsigned cvt_pk_bf16(float a, float b) {
  unsigned r;
  asm("v_cvt_pk_bf16_f32 %0, %1, %2" : "=v"(r) : "v"(a), "v"(b));
  return r;
}

__device__ __forceinline__ void load_lds16(const void* gsrc, void* ldst) {
  __builtin_amdgcn_global_load_lds(
      (const __attribute__((address_space(1))) void*)gsrc,
      (__attribute__((address_space(3))) void*)ldst, 16, 0, 0);
}

// ---------------- x fp32 -> bf16 ----------------
__global__ __launch_bounds__(256) void k_cvt(const float* __restrict__ src,
                                             short* __restrict__ dst, int n4) {
  int i = blockIdx.x * 256 + threadIdx.x;
  if (i >= n4) return;
  float4 v = ((const float4*)src)[i];
  short4 o;
  o.x = f2bf(v.x); o.y = f2bf(v.y); o.z = f2bf(v.z); o.w = f2bf(v.w);
  ((short4*)dst)[i] = o;
}

// ------------- tiled weight transpose: src [K][N] f32 -> dst [N][K] bf16 -------------
__global__ __launch_bounds__(256) void k_wt2(const float* __restrict__ src,
                                             short* __restrict__ dst, int K, int N) {
  __shared__ float tile[64][65];
  const int n0 = blockIdx.x * 64, k0 = blockIdx.y * 64;
  const int c = threadIdx.x & 63, r4 = threadIdx.x >> 6;
#pragma unroll
  for (int i = 0; i < 16; ++i) {
    int r = i * 4 + r4;
    float v = 0.f;
    if (k0 + r < K && n0 + c < N) v = src[(size_t)(k0 + r) * N + n0 + c];
    tile[r][c] = v;
  }
  __syncthreads();
#pragma unroll
  for (int i = 0; i < 16; ++i) {
    int n = i * 4 + r4;
    if (n0 + n < N && k0 + c < K)
      dst[(size_t)(n0 + n) * K + k0 + c] = f2bf(tile[c][n]);
  }
}

// ------- batched small transposes into WTsm rows z*64.. (w1w,w2w,w1r,w2r,memg) ------
__global__ __launch_bounds__(256) void k_wt5(const float* __restrict__ s0,
                                             const float* __restrict__ s1,
                                             const float* __restrict__ s2,
                                             const float* __restrict__ s3,
                                             const float* __restrict__ s4,
                                             short* __restrict__ dst) {
  __shared__ float tile[64][65];
  const int z = blockIdx.z;
  const float* src = z == 0 ? s0 : z == 1 ? s1 : z == 2 ? s2 : z == 3 ? s3 : s4;
  const int N = (z == 4) ? 16 : 64;
  const int rowoff = z * 64;
  const int k0 = blockIdx.y * 64;
  const int c = threadIdx.x & 63, r4 = threadIdx.x >> 6;
#pragma unroll
  for (int i = 0; i < 16; ++i) {
    int r = i * 4 + r4;
    float v = 0.f;
    if (c < N) v = src[(size_t)(k0 + r) * N + c];
    tile[r][c] = v;
  }
  __syncthreads();
#pragma unroll
  for (int i = 0; i < 16; ++i) {
    int n = i * 4 + r4;
    if (n < N)
      dst[(size_t)(rowoff + n) * 1024 + k0 + c] = f2bf(tile[c][n]);
  }
}

// ============ 256x256 8-phase GEMM — write-safe region schedule =====================
// BK=64, 8 waves (2M x 4N), 128KB LDS. Regions: A(d, h=mq bit6) 128x64, B(d, h=nq bit5)
// 128x64. Quadrant q=(mq,nq) reads exactly A(d,mq) + B(d,nq), so each region's last
// read phase is known; stages target only regions consumed >=1 barrier earlier:
//   q0: A.h1(kt+1)   q1: B.h1(kt+1)   q2: A.h0(kt+2)   q3: B.h0(kt+2) + vmcnt(4)
// Swizzle: LDS slot s of region-row r holds global k-chunk s^(r&7) (linear dest,
// pre-swizzled source); reads XOR the same pattern.
// acc = mfma(B_frag, A_frag). mode 0: C fp32 + bias. mode 1: qkv(3072)|memv->bf16.
__global__ __launch_bounds__(512, 2) void k_g256(
    const short* __restrict__ A, const short* __restrict__ Bt,
    const float* __restrict__ bias, float* __restrict__ C,
    const float* __restrict__ bias2,
    short* __restrict__ oq, short* __restrict__ ok_, short* __restrict__ ov,
    short* __restrict__ omv, int K, int ldc, int mode) {
  __shared__ __align__(16) short lds[65536];  // 128 KiB
  const int tid = threadIdx.x;
  const int wid = tid >> 6, lane = tid & 63;
  const int wr = wid >> 2, wc = wid & 3;      // 2M x 4N waves
  const int ql = lane & 15, g = lane >> 4;
  int m_t, n_t;
  if (mode == 1) {  // 256 blocks, XCD-chunked: xcd owns 2 m_t x 16 n_t
    int wg = blockIdx.x, xcd = wg & 7, idx = wg >> 3;
    m_t = xcd * 2 + (idx >> 4);
    n_t = idx & 15;
  } else {          // out: 16 m_t x 4 n_t
    m_t = blockIdx.x >> 2;
    n_t = blockIdx.x & 3;
  }
  const int bm = m_t * 256, bn = n_t * 256;
  const int nkt = K >> 6;
  f32x4 acc[8][4] = {};

  auto stageA = [&](int kt, int h) {
    short* base = lds + ((kt & 1) * 2 + h) * 8192;
#pragma unroll
    for (int j = 0; j < 2; ++j) {
      int o16 = j * 512 + tid;
      int rr = o16 >> 3, s = o16 & 7;
      int sp = s ^ (rr & 7);
      int grow = ((rr >> 6) << 7) + h * 64 + (rr & 63);  // row bit6 = h (=mq)
      load_lds16(A + (size_t)(bm + grow) * K + (kt << 6) + sp * 8,
                 (void*)(base + o16 * 8));
    }
  };
  auto stageB = [&](int kt, int h) {
    short* base = lds + 32768 + ((kt & 1) * 2 + h) * 8192;
#pragma unroll
    for (int j = 0; j < 2; ++j) {
      int o16 = j * 512 + tid;
      int rr = o16 >> 3, s = o16 & 7;
      int sp = s ^ (rr & 7);
      int grow = ((rr >> 5) << 6) + h * 32 + (rr & 31);  // row bit5 = h (=nq)
      load_lds16(Bt + (size_t)(bn + grow) * K + (kt << 6) + sp * 8,
                 (void*)(base + o16 * 8));
    }
  };
  auto readA = [&](int d, int mq, int mi, int kh) -> bf16x8 {
    int r = wr * 64 + mi * 16 + ql;
    int b = (r * 128 + kh * 64 + g * 16) ^ ((r & 7) << 4);
    return *(const bf16x8*)((const char*)(lds + (d * 2 + mq) * 8192) + b);
  };
  auto readB = [&](int d, int nq, int ni, int kh) -> bf16x8 {
    int r = wc * 32 + ni * 16 + ql;
    int b = (r * 128 + kh * 64 + g * 16) ^ ((r & 7) << 4);
    return *(const bf16x8*)((const char*)(lds + 32768 + (d * 2 + nq) * 8192) + b);
  };

  // prologue: kt0 all 4 half-tiles + kt1 {A.h0, B.h0} (matches steady-state invariant)
  stageA(0, 0); stageB(0, 0); stageA(0, 1); stageB(0, 1);
  stageA(1, 0); stageB(1, 0);
  asm volatile("s_waitcnt vmcnt(4)" ::: "memory");  // kt0 landed; kt1 halves in flight
  asm volatile("s_barrier" ::: "memory");

  for (int kt = 0; kt < nkt; ++kt) {
    const int d = kt & 1;
#pragma unroll
    for (int q = 0; q < 4; ++q) {
      const int mq = q >> 1, nq = q & 1;
      bf16x8 af[4][2], bfv[2][2];
#pragma unroll
      for (int mi = 0; mi < 4; ++mi)
#pragma unroll
        for (int kh = 0; kh < 2; ++kh) af[mi][kh] = readA(d, mq, mi, kh);
#pragma unroll
      for (int ni = 0; ni < 2; ++ni)
#pragma unroll
        for (int kh = 0; kh < 2; ++kh) bfv[ni][kh] = readB(d, nq, ni, kh);
      if (q == 0)      { if (kt + 1 < nkt) stageA(kt + 1, 1); }
      else if (q == 1) { if (kt + 1 < nkt) stageB(kt + 1, 1); }
      else if (q == 2) { if (kt + 2 < nkt) stageA(kt + 2, 0); }
      else             { if (kt + 2 < nkt) stageB(kt + 2, 0); }
      asm volatile("s_barrier" ::: "memory");
      __builtin_amdgcn_s_setprio(1);
#pragma unroll
      for (int kh = 0; kh < 2; ++kh)
#pragma unroll
        for (int mi = 0; mi < 4; ++mi)
#pragma unroll
          for (int ni = 0; ni < 2; ++ni)
            acc[mq * 4 + mi][nq * 2 + ni] = __builtin_amdgcn_mfma_f32_16x16x32_bf16(
                bfv[ni][kh], af[mi][kh], acc[mq * 4 + mi][nq * 2 + ni], 0, 0, 0);
      __builtin_amdgcn_s_setprio(0);
      if (q == 3) {
        if (kt + 2 < nkt)
          asm volatile("s_waitcnt vmcnt(4)" ::: "memory");  // kt+1 fully landed
        else
          asm volatile("s_waitcnt vmcnt(0)" ::: "memory");  // tail drain
      }
      asm volatile("s_barrier" ::: "memory");
    }
  }

  // epilogue: lane owns row m = bm + wr*128 + a*16 + ql, cols n0 = bn + wc*64 + c*16 + g*4
#pragma unroll
  for (int a = 0; a < 8; ++a) {
    const int m = bm + wr * 128 + a * 16 + ql;
    const int b = m >> 11, t = m & 2047;
#pragma unroll
    for (int c = 0; c < 4; ++c) {
      const int n0 = bn + wc * 64 + c * 16 + g * 4;
      f32x4 v = acc[a][c];
      if (mode == 0) {
        const float4 b4 = *(const float4*)&bias[n0];
        v[0] += b4.x; v[1] += b4.y; v[2] += b4.z; v[3] += b4.w;
        *(f32x4*)&C[(size_t)m * ldc + n0] = v;
      } else {
        if (n0 < 3072) {
          const float4 b4 = *(const float4*)&bias[n0];
          v[0] += b4.x; v[1] += b4.y; v[2] += b4.z; v[3] += b4.w;
          uint2 pk = make_uint2(cvt_pk_bf16(v[0], v[1]), cvt_pk_bf16(v[2], v[3]));
          const int sel = n0 >> 10, rem = n0 & 1023;
          if (sel == 0)
            *(uint2*)&oq[((size_t)(b * 16 + (rem >> 6)) * 2048 + t) * 64 + (rem & 63)] = pk;
          else if (sel == 1)
            *(uint2*)&ok_[((size_t)(b * 16 + (rem >> 6)) * 2048 + t) * 64 + (rem & 63)] = pk;
          else
            *(uint2*)&ov[(size_t)(b * 2048 + t) * 1024 + rem] = pk;
        } else {
          const float4 b4 = *(const float4*)&bias2[n0 - 3072];
          v[0] += b4.x; v[1] += b4.y; v[2] += b4.z; v[3] += b4.w;
          uint2 pk = make_uint2(cvt_pk_bf16(v[0], v[1]), cvt_pk_bf16(v[2], v[3]));
          *(uint2*)&omv[(size_t)(b * 2048 + t) * 1024 + n0 - 3072] = pk;
        }
      }
    }
  }
}

// ---- 64x128 GEMM (r7 structure) — used for the small sm projection only ------------
__global__ __launch_bounds__(256) void k_gemm(
    const short* __restrict__ A, const short* __restrict__ Bt,
    const float* __restrict__ bias, float* __restrict__ C,
    int K, int ldc, int ncap) {
  __shared__ short As[3][64 * 32];
  __shared__ short Bs[3][128 * 32];
  const int tid = threadIdx.x;
  const int wave = tid >> 6, lane = tid & 63;
  const int wg = blockIdx.y * gridDim.x + blockIdx.x;
  const int xcd = wg & 7, idx = wg >> 3;
  const int m_t = xcd * (gridDim.y >> 3) + idx / gridDim.x;
  const int n_t = idx % gridDim.x;
  const int bm = m_t * 64, bn = n_t * 128;
  const int mh = (wave >> 1) * 32, nh = (wave & 1) * 64;
  const int ql = lane & 15, g = lane >> 4;
  f32x4 acc[2][4] = {};
  const int kTiles = K >> 5;

  const short *agA, *agB0, *agB1;
  short *ldA, *ldB0, *ldB1;
  {
    int slot = wave * 64 + lane;
    int r = slot >> 2, u = slot & 3;
    int c = (u + 4 - ((r >> 1) & 3)) & 3;
    agA = A + (size_t)(bm + r) * K + c * 8;
    ldA = (short*)&As[0][slot * 8];
    slot = wave * 2 * 64 + lane;
    r = slot >> 2; u = slot & 3;
    c = (u + 4 - ((r >> 1) & 3)) & 3;
    agB0 = Bt + (size_t)(bn + r) * K + c * 8;
    ldB0 = (short*)&Bs[0][slot * 8];
    slot = (wave * 2 + 1) * 64 + lane;
    r = slot >> 2; u = slot & 3;
    c = (u + 4 - ((r >> 1) & 3)) & 3;
    agB1 = Bt + (size_t)(bn + r) * K + c * 8;
    ldB1 = (short*)&Bs[0][slot * 8];
  }
  const int bufStride = 64 * 32, bufStrideB = 128 * 32;
  auto stage = [&](int buf, int kt) {
    const int k0 = kt << 5;
    load_lds16(agA + k0, ldA + buf * bufStride);
    load_lds16(agB0 + k0, ldB0 + buf * bufStrideB);
    load_lds16(agB1 + k0, ldB1 + buf * bufStrideB);
  };
  stage(0, 0);
  stage(1, 1);
  int cur = 0;
  for (int kt = 0; kt < kTiles; ++kt) {
    if (kt + 1 < kTiles)
      asm volatile("s_waitcnt vmcnt(3)\n\ts_barrier" ::: "memory");
    else
      asm volatile("s_waitcnt vmcnt(0)\n\ts_barrier" ::: "memory");
    if (kt + 2 < kTiles) {
      int b2 = cur + 2; if (b2 >= 3) b2 -= 3;
      stage(b2, kt + 2);
    }
    bf16x8 af[2], bfr[4];
#pragma unroll
    for (int mi = 0; mi < 2; ++mi) {
      int row = mh + mi * 16 + ql;
      int ph = (g + (row >> 1)) & 3;
      af[mi] = *(const bf16x8*)&As[cur][row * 32 + ph * 8];
    }
#pragma unroll
    for (int ni = 0; ni < 4; ++ni) {
      int row = nh + ni * 16 + ql;
      int ph = (g + (row >> 1)) & 3;
      bfr[ni] = *(const bf16x8*)&Bs[cur][row * 32 + ph * 8];
    }
    __builtin_amdgcn_s_setprio(1);
#pragma unroll
    for (int mi = 0; mi < 2; ++mi)
#pragma unroll
      for (int ni = 0; ni < 4; ++ni)
        acc[mi][ni] = __builtin_amdgcn_mfma_f32_16x16x32_bf16(bfr[ni], af[mi],
                                                              acc[mi][ni], 0, 0, 0);
    __builtin_amdgcn_s_setprio(0);
    cur = (cur + 1 == 3) ? 0 : cur + 1;
  }
#pragma unroll
  for (int mi = 0; mi < 2; ++mi) {
    const int m = bm + mh + mi * 16 + ql;
#pragma unroll
    for (int ni = 0; ni < 4; ++ni) {
      const int n0 = bn + nh + ni * 16 + g * 4;
      if (n0 >= ncap) continue;
      f32x4 v = acc[mi][ni];
      if (bias) {
        const float4 b4 = *(const float4*)&bias[n0];
        v[0] += b4.x; v[1] += b4.y; v[2] += b4.z; v[3] += b4.w;
      }
      *(f32x4*)&C[(size_t)m * ldc + n0] = v;
    }
  }
}

// -------- V transpose + PV k-permute: vtmp [b,t,(h,dh)] -> vb [b,h,dh,tau(t)] --------
__global__ __launch_bounds__(256) void k_vtrans(const short* __restrict__ vtmp,
                                                short* __restrict__ vb) {
  __shared__ short tile[64][68];
  const int bh = blockIdx.x, b = bh >> 4, h = bh & 15;
  const int t0 = blockIdx.y * 64;
  const int tid = threadIdx.x;
#pragma unroll
  for (int pass = 0; pass < 16; ++pass) {
    int r = pass * 4 + (tid >> 6);
    int c = tid & 63;
    tile[r][c] = vtmp[((size_t)(b * 2048) + t0 + r) * 1024 + h * 64 + c];
  }
  __syncthreads();
#pragma unroll
  for (int pass = 0; pass < 16; ++pass) {
    int r = pass * 4 + (tid >> 6);  // dh
    int c = tid & 63;               // t offset within tile
    int cp = (c & 32) | (((c >> 2) & 3) << 3) | (((c >> 4) & 1) << 2) | (c & 3);
    vb[(((size_t)b * 16 + h) * 64 + r) * 2048 + t0 + cp] = tile[c][r];
  }
}

// ---------------- causal flash attention, swapped-operand, balanced pairs -----------
#define ATT_SCALE 0.18033688f  // 0.125 * log2(e)

__device__ __forceinline__ void attn_core(const bf16x8 qa[2], f32x4 o[4],
                                          float& m, float& l,
                                          const short* __restrict__ Kc,
                                          const short* __restrict__ Vc,
                                          int qt, int kt, int qglob,
                                          int ql, int g) {
  const int kv0 = kt * 64;
  f32x4 s4[4];
#pragma unroll
  for (int nt = 0; nt < 4; ++nt) {
    int krow = nt * 16 + ql;
    f32x4 s = {0.f, 0.f, 0.f, 0.f};
#pragma unroll
    for (int kc = 0; kc < 2; ++kc) {
      int sl = (kc * 4 + g) ^ (krow & 7);
      bf16x8 af = *(const bf16x8*)&Kc[krow * 64 + sl * 8];
      s = __builtin_amdgcn_mfma_f32_16x16x32_bf16(af, qa[kc], s, 0, 0, 0);
    }
    s4[nt] = s;
  }
  float mt = -1e30f;
  const bool diag = (kt == qt);
#pragma unroll
  for (int nt = 0; nt < 4; ++nt)
#pragma unroll
    for (int rg = 0; rg < 4; ++rg) {
      float v = s4[nt][rg] * ATT_SCALE;
      if (diag) {
        int kk = kv0 + nt * 16 + g * 4 + rg;
        v = (kk <= qglob) ? v : -1e30f;
      }
      s4[nt][rg] = v;
      mt = fmaxf(mt, v);
    }
  mt = fmaxf(mt, __shfl_xor(mt, 16, 64));
  mt = fmaxf(mt, __shfl_xor(mt, 32, 64));
  float mnew = fmaxf(m, mt);
  float sf = __builtin_amdgcn_exp2f(m - mnew);
  m = mnew;
  float rs = 0.f;
#pragma unroll
  for (int nt = 0; nt < 4; ++nt)
#pragma unroll
    for (int rg = 0; rg < 4; ++rg) {
      float p = __builtin_amdgcn_exp2f(s4[nt][rg] - mnew);
      s4[nt][rg] = p;
      rs += p;
    }
  rs += __shfl_xor(rs, 16, 64);
  rs += __shfl_xor(rs, 32, 64);
  l = l * sf + rs;
#pragma unroll
  for (int nt = 0; nt < 4; ++nt) o[nt] *= sf;
  bf16x8 pf[2];
#pragma unroll
  for (int kc = 0; kc < 2; ++kc) {
    u32x4 w;
    w[0] = cvt_pk_bf16(s4[2 * kc][0], s4[2 * kc][1]);
    w[1] = cvt_pk_bf16(s4[2 * kc][2], s4[2 * kc][3]);
    w[2] = cvt_pk_bf16(s4[2 * kc + 1][0], s4[2 * kc + 1][1]);
    w[3] = cvt_pk_bf16(s4[2 * kc + 1][2], s4[2 * kc + 1][3]);
    pf[kc] = __builtin_bit_cast(bf16x8, w);
  }
#pragma unroll
  for (int nt2 = 0; nt2 < 4; ++nt2) {
    int d = nt2 * 16 + ql;
#pragma unroll
    for (int kc = 0; kc < 2; ++kc) {
      int sl = (kc * 4 + g) ^ (d & 7);
      bf16x8 vf = *(const bf16x8*)&Vc[d * 64 + sl * 8];
      o[nt2] = __builtin_amdgcn_mfma_f32_16x16x32_bf16(vf, pf[kc], o[nt2], 0, 0, 0);
    }
  }
}

__device__ __forceinline__ void attn_epi(const f32x4 o[4], float l,
                                         short* __restrict__ seqo, float* ep,
                                         int b, int h, int qt, int wave, int lane) {
  const int ql = lane & 15, g = lane >> 4;
  float inv = 1.f / l;
#pragma unroll
  for (int nt2 = 0; nt2 < 4; ++nt2) {
    f32x4 v = o[nt2] * inv;
    *(f32x4*)&ep[ql * 64 + (((nt2 * 4 + g) ^ (ql & 7)) << 2)] = v;
  }
  short* srow = seqo + ((size_t)b * 2048 + qt * 64 + wave * 16) * 1024 + h * 64;
#pragma unroll
  for (int p = 0; p < 8; ++p) {
    int prow = p * 2 + (lane >> 5);
    int d2 = (lane & 31) * 2;
    const float* rp = &ep[prow * 64 + (((d2 >> 2) ^ (prow & 7)) << 2) + (d2 & 3)];
    float2 vv = *(const float2*)rp;
    *(unsigned*)&srow[(size_t)prow * 1024 + d2] = cvt_pk_bf16(vv.x, vv.y);
  }
}

__global__ __launch_bounds__(512, 4) void k_attn(const short* __restrict__ Q,
                                                 const short* __restrict__ Kg,
                                                 const short* __restrict__ Vg,
                                                 short* __restrict__ seqo) {
  __shared__ short Kt[2][2][64 * 64];  // [half][buf]
  __shared__ short Vt[2][2][64 * 64];
  const int wg = blockIdx.x;
  const int x = wg & 7, s = wg >> 3;
  const int bh = 4 * x + (s >> 3);
  const int tid = threadIdx.x;
  const int half = tid >> 8;
  const int pi = ((s & 7) << 1) + half;
  const int qtA = pi, qtB = 31 - pi;
  const int b = bh >> 4, h = bh & 15;
  const int wave = (tid >> 6) & 3, lane = tid & 63;
  const int ql = lane & 15, g = lane >> 4;
  const short* qbase = Q + (size_t)bh * 2048 * 64;
  const int qgA = qtA * 64 + wave * 16 + ql;
  const int qgB = qtB * 64 + wave * 16 + ql;
  bf16x8 qaA[2], qaB[2];
  {
    const short* qr = qbase + (size_t)qgA * 64;
    qaA[0] = *(const bf16x8*)&qr[g * 8];
    qaA[1] = *(const bf16x8*)&qr[32 + g * 8];
    qr = qbase + (size_t)qgB * 64;
    qaB[0] = *(const bf16x8*)&qr[g * 8];
    qaB[1] = *(const bf16x8*)&qr[32 + g * 8];
  }
  f32x4 oA[4] = {}, oB[4] = {};
  float mA = -1e30f, lA = 0.f, mB = -1e30f, lB = 0.f;
  const short* kgb = Kg + (size_t)bh * 2048 * 64;
  const short* vgb = Vg + (size_t)bh * 64 * 2048;

  auto stage = [&](int buf, int kt) {
    int kv0 = kt * 64;
#pragma unroll
    for (int j = 0; j < 2; ++j) {
      int slot = (wave * 2 + j) * 64 + lane;
      int r = slot >> 3, s8 = slot & 7;
      int ss = s8 ^ (r & 7);
      load_lds16(kgb + (size_t)(kv0 + r) * 64 + ss * 8, &Kt[half][buf][slot * 8]);
      load_lds16(vgb + (size_t)r * 2048 + kv0 + ss * 8, &Vt[half][buf][slot * 8]);
    }
  };

  stage(0, 0);
  int cur = 0;
  for (int it = 0; it < 33; ++it) {
    __syncthreads();
    if (it < 32) {
      int nit = it + 1;
      int nkt2 = (nit <= qtB) ? nit : nit - qtB - 1;
      stage(cur ^ 1, nkt2);
    }
    const short* Kc = Kt[half][cur];
    const short* Vc = Vt[half][cur];
    if (it <= qtB)
      attn_core(qaB, oB, mB, lB, Kc, Vc, qtB, it, qgB, ql, g);
    else
      attn_core(qaA, oA, mA, lA, Kc, Vc, qtA, it - qtB - 1, qgA, ql, g);
    cur ^= 1;
  }
  __syncthreads();
  float* ep = (float*)&Kt[half][0][0] + wave * 1024;
  attn_epi(oB, lB, seqo, ep, b, h, qtB, wave, lane);
  attn_epi(oA, lA, seqo, ep, b, h, qtA, wave, lane);
}

// ---------------- Plücker lines: Csm [b,t,272] -> u=(wl@J)/|wl|, r=rl/|rl| ----------
__global__ __launch_bounds__(256) void k_lines(const float* __restrict__ Cs,
                                               const float* __restrict__ Jm,
                                               float* __restrict__ u,
                                               float* __restrict__ rr) {
  int idx = blockIdx.x * 256 + threadIdx.x;
  if (idx >= 2 * 2048 * 16) return;
  int h = idx & 15, t = (idx >> 4) & 2047, b = idx >> 15;
  const float* rowx = Cs + (size_t)(b * 2048 + t) * 272;
  float w1[4], w2[4], r1[4], r2[4];
  if (t == 0) {
#pragma unroll
    for (int i = 0; i < 4; ++i) w1[i] = 0.f;
  } else {
    const float* prev = Cs + (size_t)(b * 2048 + t - 1) * 272;
#pragma unroll
    for (int i = 0; i < 4; ++i) w1[i] = prev[h * 4 + i];
  }
#pragma unroll
  for (int i = 0; i < 4; ++i) {
    w2[i] = rowx[64 + h * 4 + i];
    r1[i] = rowx[128 + h * 4 + i];
    r2[i] = rowx[192 + h * 4 + i];
  }
  const int pi[6] = {0, 0, 0, 1, 1, 2}, pj[6] = {1, 2, 3, 2, 3, 3};
  float wl[6], rl[6], nw = 0.f, nr = 0.f;
#pragma unroll
  for (int e = 0; e < 6; ++e) {
    wl[e] = w1[pi[e]] * w2[pj[e]] - w1[pj[e]] * w2[pi[e]];
    rl[e] = r1[pi[e]] * r2[pj[e]] - r1[pj[e]] * r2[pi[e]];
    nw += wl[e] * wl[e];
    nr += rl[e] * rl[e];
  }
  nw = 1.f / fmaxf(sqrtf(nw), 1e-12f);
  nr = 1.f / fmaxf(sqrtf(nr), 1e-12f);
  size_t base = (((size_t)b * 16 + h) * 2048 + t) * 6;
#pragma unroll
  for (int jc = 0; jc < 6; ++jc) {
    float s = 0.f;
#pragma unroll
    for (int i = 0; i < 6; ++i) s += wl[i] * Jm[i * 6 + jc];
    u[base + jc] = s * nw;
    rr[base + jc] = rl[jc] * nr;
  }
}

// ------------- decayed prefix scan per channel: w[bh][ch][t] = S_t[p][q] -------------
__global__ __launch_bounds__(256) void k_scanw(const float* __restrict__ u,
                                               float* __restrict__ w,
                                               const float* __restrict__ decays) {
  __shared__ float wtot[4];
  const int ch = blockIdx.x;
  const int bh = blockIdx.y;
  const float d = decays[bh & 15];
  const int p = ch / 6, q = ch % 6;
  const int tid = threadIdx.x, lane = tid & 63, wv = tid >> 6;
  const float* ub = u + (size_t)bh * 2048 * 6;
  const int t0 = tid * 8;
  float z[8];
  float a = 0.f;
#pragma unroll
  for (int i = 0; i < 8; ++i) {
    float up = ub[(t0 + i) * 6 + p], uq = ub[(t0 + i) * 6 + q];
    z[i] = up * uq;
    a = d * (a + z[i]);
  }
  float d8 = d * d; d8 *= d8; d8 *= d8;
  float I = a;
  float ds = d8;
#pragma unroll
  for (int s = 1; s < 64; s <<= 1) {
    float v = __shfl_up(I, s, 64);
    if (lane >= s) I += ds * v;
    ds *= ds;
  }
  if (lane == 63) wtot[wv] = I;
  __syncthreads();
  float carry = 0.f;
  for (int w2 = 0; w2 < wv; ++w2) carry = carry * ds + wtot[w2];
  float dlp1 = exp2f(log2f(d8) * (float)(lane + 1));
  float Ig = I + dlp1 * carry;
  float E = __shfl_up(Ig, 1, 64);
  if (lane == 0) E = carry;
  float S = E;
  float out[8];
#pragma unroll
  for (int i = 0; i < 8; ++i) {
    out[i] = S;
    S = d * (S + z[i]);
  }
  float4* wp = (float4*)(w + ((size_t)bh * 36 + ch) * 2048 + t0);
  wp[0] = make_float4(out[0], out[1], out[2], out[3]);
  wp[1] = make_float4(out[4], out[5], out[6], out[7]);
}

// ------------- scores[bh][t] = sum_ch r[p]*r[q] * w[bh][ch][t] ----------------------
__global__ __launch_bounds__(256) void k_scandot(const float* __restrict__ rr,
                                                 const float* __restrict__ w,
                                                 float* __restrict__ scores) {
  const int bh = blockIdx.y;
  const int t = blockIdx.x * 256 + threadIdx.x;
  const float* rb = rr + ((size_t)bh * 2048 + t) * 6;
  float r[6];
#pragma unroll
  for (int i = 0; i < 6; ++i) r[i] = rb[i];
  const float* wb = w + (size_t)bh * 36 * 2048 + t;
  float acc = 0.f;
#pragma unroll
  for (int ch = 0; ch < 36; ++ch)
    acc += r[ch / 6] * r[ch % 6] * wb[(size_t)ch * 2048];
  scores[(size_t)bh * 2048 + t] = acc;
}

// ---------------- gate: gmean[b,t] = mean_h sig(score*scale_h)*sig(memg) -----------
__global__ __launch_bounds__(256) void k_gate(const float* __restrict__ scores,
                                              const float* __restrict__ Cs,
                                              const float* __restrict__ memg_b,
                                              const float* __restrict__ mem_scale,
                                              float* __restrict__ gmean) {
  int idx = blockIdx.x * 256 + threadIdx.x;
  if (idx >= BT) return;
  int b = idx >> 11, t = idx & 2047;
  float acc = 0.f;
#pragma unroll
  for (int h = 0; h < 16; ++h) {
    float s = scores[((size_t)(b * 16 + h) * 2048) + t];
    float gl = Cs[(size_t)idx * 272 + 256 + h] + memg_b[h];
    float a = 1.f / (1.f + __expf(-s * mem_scale[h]));
    float gg = 1.f / (1.f + __expf(-gl));
    acc += a * gg;
  }
  gmean[idx] = acc * (1.f / 16.f);
}

// ---------------- fuse: Fb = bf16(seq_bf16 + gmean*memval_bf16) ----------------
__global__ __launch_bounds__(256) void k_fuse(const short* __restrict__ s,
                                              const short* __restrict__ mv,
                                              const float* __restrict__ gm,
                                              short* __restrict__ dst, int n4) {
  int i = blockIdx.x * 256 + threadIdx.x;
  if (i >= n4) return;
  float gg = gm[i >> 8];
  short4 a = ((const short4*)s)[i];
  short4 m = ((const short4*)mv)[i];
  short4 o;
  o.x = f2bf(bf2f(a.x) + gg * bf2f(m.x));
  o.y = f2bf(bf2f(a.y) + gg * bf2f(m.y));
  o.z = f2bf(bf2f(a.z) + gg * bf2f(m.z));
  o.w = f2bf(bf2f(a.w) + gg * bf2f(m.w));
  ((short4*)dst)[i] = o;
}

extern "C" void kernel_launch(void* const* d_in, const int* in_sizes, int n_in,
                              void* d_out, int out_size, void* d_ws, size_t ws_size,
                              hipStream_t stream) {
  const float* x = (const float*)d_in[0];
  const float* qkv_w = (const float*)d_in[1];
  const float* qkv_b = (const float*)d_in[2];
  const float* w1w = (const float*)d_in[3];
  const float* w2w = (const float*)d_in[4];
  const float* w1r = (const float*)d_in[5];
  const float* w2r = (const float*)d_in[6];
  const float* memv_w = (const float*)d_in[7];
  const float* memv_b = (const float*)d_in[8];
  const float* memg_w = (const float*)d_in[9];
  const float* memg_b = (const float*)d_in[10];
  const float* mem_scale = (const float*)d_in[11];
  const float* out_w = (const float*)d_in[12];
  const float* out_b = (const float*)d_in[13];
  const float* Jm = (const float*)d_in[14];
  const float* decays = (const float*)d_in[15];

  char* w = (char*)d_ws;
  size_t off = 0;
  auto alloc = [&](size_t bytes) -> void* {
    void* p = w + off;
    off += (bytes + 255) & ~(size_t)255;
    return p;
  };
  short* xb = (short*)alloc((size_t)BT * Dd * 2);
  short* WTall = (short*)alloc((size_t)4096 * 1024 * 2);  // qkv(3072)|memv(1024)
  short* WTsm = (short*)alloc((size_t)384 * 1024 * 2);    // w1|w2|r1|r2|memg
  short* WTout = (short*)alloc((size_t)1024 * 1024 * 2);
  short* qb = (short*)alloc((size_t)32 * 2048 * 64 * 2);
  short* kb = (short*)alloc((size_t)32 * 2048 * 64 * 2);
  short* vtmp = (short*)alloc((size_t)BT * 1024 * 2);
  short* vb = (short*)alloc((size_t)32 * 64 * 2048 * 2);
  float* Csm = (float*)alloc((size_t)BT * 272 * 4);
  float* ua = (float*)alloc((size_t)32 * 2048 * 6 * 4);
  float* ra = (float*)alloc((size_t)32 * 2048 * 6 * 4);
  float* sc = (float*)alloc((size_t)32 * 2048 * 4);
  float* gm = (float*)alloc((size_t)BT * 4);
  short* mvb = (short*)alloc((size_t)BT * 1024 * 2);
  short* seqo = (short*)alloc((size_t)BT * 1024 * 2);
  short* Fb = (short*)alloc((size_t)BT * Dd * 2);
  float* wscan = (float*)qb;  // aliases qb+kb, dead after k_attn
  (void)ws_size; (void)in_sizes; (void)n_in; (void)out_size;

  // prep
  k_cvt<<<(BT * Dd / 4 + 255) / 256, 256, 0, stream>>>(x, xb, BT * Dd / 4);
  k_wt2<<<dim3(48, 16), 256, 0, stream>>>(qkv_w, WTall, 1024, 3072);
  k_wt2<<<dim3(16, 16), 256, 0, stream>>>(memv_w, WTall + (size_t)3072 * 1024, 1024, 1024);
  k_wt5<<<dim3(1, 16, 5), 256, 0, stream>>>(w1w, w2w, w1r, w2r, memg_w, WTsm);
  k_wt2<<<dim3(16, 16), 256, 0, stream>>>(out_w, WTout, 1024, 1024);

  // fused 256^2 8-phase GEMM: qkv (3072) | memv (1024, ->bf16) over N=4096, grid=256
  k_g256<<<256, 512, 0, stream>>>(xb, WTall, qkv_b, nullptr, memv_b,
                                  qb, kb, vtmp, mvb, 1024, 0, 1);
  // sm projections (N=272, padded B to 384)
  k_gemm<<<dim3(3, 64), 256, 0, stream>>>(xb, WTsm, nullptr, Csm, 1024, 272, 272);

  k_vtrans<<<dim3(32, 32), 256, 0, stream>>>(vtmp, vb);

  // attention: 256 balanced blocks x 512 threads
  k_attn<<<256, 512, 0, stream>>>(qb, kb, vb, seqo);

  // memory path
  k_lines<<<(2 * 2048 * 16 + 255) / 256, 256, 0, stream>>>(Csm, Jm, ua, ra);
  k_scanw<<<dim3(36, 32), 256, 0, stream>>>(ua, wscan, decays);
  k_scandot<<<dim3(8, 32), 256, 0, stream>>>(ra, wscan, sc);
  k_gate<<<(BT + 255) / 256, 256, 0, stream>>>(sc, Csm, memg_b, mem_scale, gm);

  // fuse + final 256^2 GEMM (N=1024, grid 16x4)
  k_fuse<<<(BT * Dd / 4 + 255) / 256, 256, 0, stream>>>(seqo, mvb, gm, Fb, BT * Dd / 4);
  k_g256<<<64, 512, 0, stream>>>(Fb, WTout, out_b, (float*)d_out, nullptr,
                                 nullptr, nullptr, nullptr, nullptr, 1024, 1024, 0);
}

// Round 10
// 233.558 us; speedup vs baseline: 1.0081x; 1.0081x over previous
//
#include <hip/hip_runtime.h>

#define BT 4096      // B*T
#define Dd 1024
#define Tt 2048

typedef __attribute__((ext_vector_type(8))) short bf16x8;
typedef __attribute__((ext_vector_type(4))) float f32x4;
typedef __attribute__((ext_vector_type(4))) unsigned u32x4;

__device__ __forceinline__ short f2bf(float f) {
  unsigned u = __builtin_bit_cast(unsigned, f);
  u = (u + 0x7FFFu + ((u >> 16) & 1u)) >> 16;
  return (short)u;
}
__device__ __forceinline__ float bf2f(short s) {
  unsigned u = ((unsigned)(unsigned short)s) << 16;
  return __builtin_bit_cast(float, u);
}
__device__ __forceinline__ unsigned cvt_pk_bf16(float a, float b) {
  unsigned r;
  asm("v_cvt_pk_bf16_f32 %0, %1, %2" : "=v"(r) : "v"(a), "v"(b));
  return r;
}

__device__ __forceinline__ void load_lds16(const void* gsrc, void* ldst) {
  __builtin_amdgcn_global_load_lds(
      (const __attribute__((address_space(1))) void*)gsrc,
      (__attribute__((address_space(3))) void*)ldst, 16, 0, 0);
}

// ---------------- x fp32 -> bf16 ----------------
__global__ __launch_bounds__(256) void k_cvt(const float* __restrict__ src,
                                             short* __restrict__ dst, int n4) {
  int i = blockIdx.x * 256 + threadIdx.x;
  if (i >= n4) return;
  float4 v = ((const float4*)src)[i];
  short4 o;
  o.x = f2bf(v.x); o.y = f2bf(v.y); o.z = f2bf(v.z); o.w = f2bf(v.w);
  ((short4*)dst)[i] = o;
}

// ------------- tiled weight transpose: src [K][N] f32 -> dst [N][K] bf16 -------------
__global__ __launch_bounds__(256) void k_wt2(const float* __restrict__ src,
                                             short* __restrict__ dst, int K, int N) {
  __shared__ float tile[64][65];
  const int n0 = blockIdx.x * 64, k0 = blockIdx.y * 64;
  const int c = threadIdx.x & 63, r4 = threadIdx.x >> 6;
#pragma unroll
  for (int i = 0; i < 16; ++i) {
    int r = i * 4 + r4;
    float v = 0.f;
    if (k0 + r < K && n0 + c < N) v = src[(size_t)(k0 + r) * N + n0 + c];
    tile[r][c] = v;
  }
  __syncthreads();
#pragma unroll
  for (int i = 0; i < 16; ++i) {
    int n = i * 4 + r4;
    if (n0 + n < N && k0 + c < K)
      dst[(size_t)(n0 + n) * K + k0 + c] = f2bf(tile[c][n]);
  }
}

// ------- batched small transposes into WTsm rows z*64.. (w1w,w2w,w1r,w2r,memg) ------
__global__ __launch_bounds__(256) void k_wt5(const float* __restrict__ s0,
                                             const float* __restrict__ s1,
                                             const float* __restrict__ s2,
                                             const float* __restrict__ s3,
                                             const float* __restrict__ s4,
                                             short* __restrict__ dst) {
  __shared__ float tile[64][65];
  const int z = blockIdx.z;
  const float* src = z == 0 ? s0 : z == 1 ? s1 : z == 2 ? s2 : z == 3 ? s3 : s4;
  const int N = (z == 4) ? 16 : 64;
  const int rowoff = z * 64;
  const int k0 = blockIdx.y * 64;
  const int c = threadIdx.x & 63, r4 = threadIdx.x >> 6;
#pragma unroll
  for (int i = 0; i < 16; ++i) {
    int r = i * 4 + r4;
    float v = 0.f;
    if (c < N) v = src[(size_t)(k0 + r) * N + c];
    tile[r][c] = v;
  }
  __syncthreads();
#pragma unroll
  for (int i = 0; i < 16; ++i) {
    int n = i * 4 + r4;
    if (n < N)
      dst[(size_t)(rowoff + n) * 1024 + k0 + c] = f2bf(tile[c][n]);
  }
}

// ============ 256x256 8-phase GEMM — hoisted addresses, manual phase unroll =========
// Same verified region/swizzle mapping as r9. Regions (16KB each):
//   A(d,h): bytes (d*2+h)*16384          rows: b*128 + h*64 + lo   (h = mq)
//   B(d,h): bytes 65536 + (d*2+h)*16384  rows: b*64  + h*32 + lo   (h = nq)
// Read byte within region: r*128 + ((chunk)^(r&7))*16, chunk = kh*4+g  (lane-const XOR
// folded into 4 base pointers). Stage: linear LDS dest + pre-swizzled global source.
__global__ __launch_bounds__(512, 2) void k_g256(
    const short* __restrict__ A, const short* __restrict__ Bt,
    const float* __restrict__ bias, float* __restrict__ C,
    const float* __restrict__ bias2,
    short* __restrict__ oq, short* __restrict__ ok_, short* __restrict__ ov,
    short* __restrict__ omv, int K, int ldc, int mode) {
  __shared__ __align__(16) short lds[65536];  // 128 KiB
  const int tid = threadIdx.x;
  const int wid = tid >> 6, lane = tid & 63;
  const int wr = wid >> 2, wc = wid & 3;      // 2M x 4N waves
  const int ql = lane & 15, g = lane >> 4;
  int m_t, n_t;
  if (mode == 1) {  // 256 blocks, XCD-chunked: xcd owns 2 m_t x 16 n_t
    int wg = blockIdx.x, xcd = wg & 7, idx = wg >> 3;
    m_t = xcd * 2 + (idx >> 4);
    n_t = idx & 15;
  } else {          // out: 16 m_t x 4 n_t
    m_t = blockIdx.x >> 2;
    n_t = blockIdx.x & 3;
  }
  const int bm = m_t * 256, bn = n_t * 256;
  const int nkt = K >> 6;
  f32x4 acc[8][4] = {};

  // ---- hoisted stage addressing (per-lane constants) ----
  const short* srcA[2][2];  // [h][j]
  const short* srcB[2][2];
  short* dstA[2];
  short* dstB[2];
#pragma unroll
  for (int j = 0; j < 2; ++j) {
    int o16 = j * 512 + tid;
    int rr = o16 >> 3, s = o16 & 7;
    int sp = s ^ (rr & 7);
#pragma unroll
    for (int h = 0; h < 2; ++h) {
      int growA = ((rr >> 6) << 7) + h * 64 + (rr & 63);
      int growB = ((rr >> 5) << 6) + h * 32 + (rr & 31);
      srcA[h][j] = A + (size_t)(bm + growA) * K + sp * 8;
      srcB[h][j] = Bt + (size_t)(bn + growB) * K + sp * 8;
    }
    dstA[j] = lds + o16 * 8;
    dstB[j] = lds + 32768 + o16 * 8;
  }
#define STG_A(H, DP, KT)                                                      \
  do {                                                                        \
    load_lds16(srcA[H][0] + ((KT) << 6), dstA[0] + ((DP)*2 + (H)) * 8192);    \
    load_lds16(srcA[H][1] + ((KT) << 6), dstA[1] + ((DP)*2 + (H)) * 8192);    \
  } while (0)
#define STG_B(H, DP, KT)                                                      \
  do {                                                                        \
    load_lds16(srcB[H][0] + ((KT) << 6), dstB[0] + ((DP)*2 + (H)) * 8192);    \
    load_lds16(srcB[H][1] + ((KT) << 6), dstB[1] + ((DP)*2 + (H)) * 8192);    \
  } while (0)

  // ---- hoisted read bases (swizzle XOR folded in; kh=0/1 variants) ----
  const int q7 = ql & 7;
  const char* baseA0 = (const char*)lds + wr * 8192 + ql * 128 + ((g ^ q7) << 4);
  const char* baseA1 = (const char*)lds + wr * 8192 + ql * 128 + (((g + 4) ^ q7) << 4);
  const char* baseB0 =
      (const char*)lds + 65536 + wc * 4096 + ql * 128 + ((g ^ q7) << 4);
  const char* baseB1 =
      (const char*)lds + 65536 + wc * 4096 + ql * 128 + (((g + 4) ^ q7) << 4);

#define PHASE(MQ, NQ, STAGE_STMT, WAIT_STMT)                                   \
  do {                                                                         \
    bf16x8 af[4][2], bv[2][2];                                                 \
    _Pragma("unroll") for (int mi = 0; mi < 4; ++mi) {                         \
      af[mi][0] = *(const bf16x8*)(baseA0 + dOff + (MQ)*16384 + mi * 2048);    \
      af[mi][1] = *(const bf16x8*)(baseA1 + dOff + (MQ)*16384 + mi * 2048);    \
    }                                                                          \
    _Pragma("unroll") for (int ni = 0; ni < 2; ++ni) {                         \
      bv[ni][0] = *(const bf16x8*)(baseB0 + dOff + (NQ)*16384 + ni * 2048);    \
      bv[ni][1] = *(const bf16x8*)(baseB1 + dOff + (NQ)*16384 + ni * 2048);    \
    }                                                                          \
    STAGE_STMT;                                                                \
    __builtin_amdgcn_s_barrier();                                              \
    asm volatile("s_waitcnt lgkmcnt(0)" ::: "memory");                         \
    __builtin_amdgcn_s_setprio(1);                                             \
    _Pragma("unroll") for (int kh = 0; kh < 2; ++kh)                           \
        _Pragma("unroll") for (int mi = 0; mi < 4; ++mi)                       \
            _Pragma("unroll") for (int ni = 0; ni < 2; ++ni)                   \
                acc[(MQ)*4 + mi][(NQ)*2 + ni] =                                \
        __builtin_amdgcn_mfma_f32_16x16x32_bf16(                               \
            bv[ni][kh], af[mi][kh], acc[(MQ)*4 + mi][(NQ)*2 + ni], 0, 0, 0);   \
    __builtin_amdgcn_s_setprio(0);                                             \
    WAIT_STMT;                                                                 \
    __builtin_amdgcn_s_barrier();                                              \
  } while (0)

  // prologue: kt0 all 4 half-tiles + kt1 {A.h0, B.h0}
  STG_A(0, 0, 0); STG_B(0, 0, 0); STG_A(1, 0, 0); STG_B(1, 0, 0);
  STG_A(0, 1, 1); STG_B(0, 1, 1);
  asm volatile("s_waitcnt vmcnt(4)" ::: "memory");
  __builtin_amdgcn_s_barrier();

  for (int kt = 0; kt < nkt; ++kt) {
    const int dOff = (kt & 1) << 15;  // byte offset of current dbuf
    const int dn = (kt + 1) & 1, dn2 = (kt + 2) & 1;
    const bool s1 = kt + 1 < nkt, s2 = kt + 2 < nkt;
    PHASE(0, 0, { if (s1) STG_A(1, dn, kt + 1); }, {});
    PHASE(0, 1, { if (s1) STG_B(1, dn, kt + 1); }, {});
    PHASE(1, 0, { if (s2) STG_A(0, dn2, kt + 2); }, {});
    PHASE(1, 1, { if (s2) STG_B(0, dn2, kt + 2); }, {
      if (s2) asm volatile("s_waitcnt vmcnt(4)" ::: "memory");
      else    asm volatile("s_waitcnt vmcnt(0)" ::: "memory");
    });
  }
#undef PHASE
#undef STG_A
#undef STG_B

  // epilogue: lane owns row m = bm + wr*128 + a*16 + ql, cols n0 = bn + wc*64 + c*16 + g*4
#pragma unroll
  for (int a = 0; a < 8; ++a) {
    const int m = bm + wr * 128 + a * 16 + ql;
    const int b = m >> 11, t = m & 2047;
#pragma unroll
    for (int c = 0; c < 4; ++c) {
      const int n0 = bn + wc * 64 + c * 16 + g * 4;
      f32x4 v = acc[a][c];
      if (mode == 0) {
        const float4 b4 = *(const float4*)&bias[n0];
        v[0] += b4.x; v[1] += b4.y; v[2] += b4.z; v[3] += b4.w;
        *(f32x4*)&C[(size_t)m * ldc + n0] = v;
      } else {
        if (n0 < 3072) {
          const float4 b4 = *(const float4*)&bias[n0];
          v[0] += b4.x; v[1] += b4.y; v[2] += b4.z; v[3] += b4.w;
          uint2 pk = make_uint2(cvt_pk_bf16(v[0], v[1]), cvt_pk_bf16(v[2], v[3]));
          const int sel = n0 >> 10, rem = n0 & 1023;
          if (sel == 0)
            *(uint2*)&oq[((size_t)(b * 16 + (rem >> 6)) * 2048 + t) * 64 + (rem & 63)] = pk;
          else if (sel == 1)
            *(uint2*)&ok_[((size_t)(b * 16 + (rem >> 6)) * 2048 + t) * 64 + (rem & 63)] = pk;
          else
            *(uint2*)&ov[(size_t)(b * 2048 + t) * 1024 + rem] = pk;
        } else {
          const float4 b4 = *(const float4*)&bias2[n0 - 3072];
          v[0] += b4.x; v[1] += b4.y; v[2] += b4.z; v[3] += b4.w;
          uint2 pk = make_uint2(cvt_pk_bf16(v[0], v[1]), cvt_pk_bf16(v[2], v[3]));
          *(uint2*)&omv[(size_t)(b * 2048 + t) * 1024 + n0 - 3072] = pk;
        }
      }
    }
  }
}

// ---- 64x128 GEMM (r7 structure) — used for the small sm projection only ------------
__global__ __launch_bounds__(256) void k_gemm(
    const short* __restrict__ A, const short* __restrict__ Bt,
    const float* __restrict__ bias, float* __restrict__ C,
    int K, int ldc, int ncap) {
  __shared__ short As[3][64 * 32];
  __shared__ short Bs[3][128 * 32];
  const int tid = threadIdx.x;
  const int wave = tid >> 6, lane = tid & 63;
  const int wg = blockIdx.y * gridDim.x + blockIdx.x;
  const int xcd = wg & 7, idx = wg >> 3;
  const int m_t = xcd * (gridDim.y >> 3) + idx / gridDim.x;
  const int n_t = idx % gridDim.x;
  const int bm = m_t * 64, bn = n_t * 128;
  const int mh = (wave >> 1) * 32, nh = (wave & 1) * 64;
  const int ql = lane & 15, g = lane >> 4;
  f32x4 acc[2][4] = {};
  const int kTiles = K >> 5;

  const short *agA, *agB0, *agB1;
  short *ldA, *ldB0, *ldB1;
  {
    int slot = wave * 64 + lane;
    int r = slot >> 2, u = slot & 3;
    int c = (u + 4 - ((r >> 1) & 3)) & 3;
    agA = A + (size_t)(bm + r) * K + c * 8;
    ldA = (short*)&As[0][slot * 8];
    slot = wave * 2 * 64 + lane;
    r = slot >> 2; u = slot & 3;
    c = (u + 4 - ((r >> 1) & 3)) & 3;
    agB0 = Bt + (size_t)(bn + r) * K + c * 8;
    ldB0 = (short*)&Bs[0][slot * 8];
    slot = (wave * 2 + 1) * 64 + lane;
    r = slot >> 2; u = slot & 3;
    c = (u + 4 - ((r >> 1) & 3)) & 3;
    agB1 = Bt + (size_t)(bn + r) * K + c * 8;
    ldB1 = (short*)&Bs[0][slot * 8];
  }
  const int bufStride = 64 * 32, bufStrideB = 128 * 32;
  auto stage = [&](int buf, int kt) {
    const int k0 = kt << 5;
    load_lds16(agA + k0, ldA + buf * bufStride);
    load_lds16(agB0 + k0, ldB0 + buf * bufStrideB);
    load_lds16(agB1 + k0, ldB1 + buf * bufStrideB);
  };
  stage(0, 0);
  stage(1, 1);
  int cur = 0;
  for (int kt = 0; kt < kTiles; ++kt) {
    if (kt + 1 < kTiles)
      asm volatile("s_waitcnt vmcnt(3)\n\ts_barrier" ::: "memory");
    else
      asm volatile("s_waitcnt vmcnt(0)\n\ts_barrier" ::: "memory");
    if (kt + 2 < kTiles) {
      int b2 = cur + 2; if (b2 >= 3) b2 -= 3;
      stage(b2, kt + 2);
    }
    bf16x8 af[2], bfr[4];
#pragma unroll
    for (int mi = 0; mi < 2; ++mi) {
      int row = mh + mi * 16 + ql;
      int ph = (g + (row >> 1)) & 3;
      af[mi] = *(const bf16x8*)&As[cur][row * 32 + ph * 8];
    }
#pragma unroll
    for (int ni = 0; ni < 4; ++ni) {
      int row = nh + ni * 16 + ql;
      int ph = (g + (row >> 1)) & 3;
      bfr[ni] = *(const bf16x8*)&Bs[cur][row * 32 + ph * 8];
    }
    __builtin_amdgcn_s_setprio(1);
#pragma unroll
    for (int mi = 0; mi < 2; ++mi)
#pragma unroll
      for (int ni = 0; ni < 4; ++ni)
        acc[mi][ni] = __builtin_amdgcn_mfma_f32_16x16x32_bf16(bfr[ni], af[mi],
                                                              acc[mi][ni], 0, 0, 0);
    __builtin_amdgcn_s_setprio(0);
    cur = (cur + 1 == 3) ? 0 : cur + 1;
  }
#pragma unroll
  for (int mi = 0; mi < 2; ++mi) {
    const int m = bm + mh + mi * 16 + ql;
#pragma unroll
    for (int ni = 0; ni < 4; ++ni) {
      const int n0 = bn + nh + ni * 16 + g * 4;
      if (n0 >= ncap) continue;
      f32x4 v = acc[mi][ni];
      if (bias) {
        const float4 b4 = *(const float4*)&bias[n0];
        v[0] += b4.x; v[1] += b4.y; v[2] += b4.z; v[3] += b4.w;
      }
      *(f32x4*)&C[(size_t)m * ldc + n0] = v;
    }
  }
}

// -------- V transpose + PV k-permute: vtmp [b,t,(h,dh)] -> vb [b,h,dh,tau(t)] --------
__global__ __launch_bounds__(256) void k_vtrans(const short* __restrict__ vtmp,
                                                short* __restrict__ vb) {
  __shared__ short tile[64][68];
  const int bh = blockIdx.x, b = bh >> 4, h = bh & 15;
  const int t0 = blockIdx.y * 64;
  const int tid = threadIdx.x;
#pragma unroll
  for (int pass = 0; pass < 16; ++pass) {
    int r = pass * 4 + (tid >> 6);
    int c = tid & 63;
    tile[r][c] = vtmp[((size_t)(b * 2048) + t0 + r) * 1024 + h * 64 + c];
  }
  __syncthreads();
#pragma unroll
  for (int pass = 0; pass < 16; ++pass) {
    int r = pass * 4 + (tid >> 6);  // dh
    int c = tid & 63;               // t offset within tile
    int cp = (c & 32) | (((c >> 2) & 3) << 3) | (((c >> 4) & 1) << 2) | (c & 3);
    vb[(((size_t)b * 16 + h) * 64 + r) * 2048 + t0 + cp] = tile[c][r];
  }
}

// ---------------- causal flash attention, swapped-operand, balanced pairs -----------
#define ATT_SCALE 0.18033688f  // 0.125 * log2(e)

__device__ __forceinline__ void attn_core(const bf16x8 qa[2], f32x4 o[4],
                                          float& m, float& l,
                                          const short* __restrict__ Kc,
                                          const short* __restrict__ Vc,
                                          int qt, int kt, int qglob,
                                          int ql, int g) {
  const int kv0 = kt * 64;
  f32x4 s4[4];
#pragma unroll
  for (int nt = 0; nt < 4; ++nt) {
    int krow = nt * 16 + ql;
    f32x4 s = {0.f, 0.f, 0.f, 0.f};
#pragma unroll
    for (int kc = 0; kc < 2; ++kc) {
      int sl = (kc * 4 + g) ^ (krow & 7);
      bf16x8 af = *(const bf16x8*)&Kc[krow * 64 + sl * 8];
      s = __builtin_amdgcn_mfma_f32_16x16x32_bf16(af, qa[kc], s, 0, 0, 0);
    }
    s4[nt] = s;
  }
  float mt = -1e30f;
  const bool diag = (kt == qt);
#pragma unroll
  for (int nt = 0; nt < 4; ++nt)
#pragma unroll
    for (int rg = 0; rg < 4; ++rg) {
      float v = s4[nt][rg] * ATT_SCALE;
      if (diag) {
        int kk = kv0 + nt * 16 + g * 4 + rg;
        v = (kk <= qglob) ? v : -1e30f;
      }
      s4[nt][rg] = v;
      mt = fmaxf(mt, v);
    }
  mt = fmaxf(mt, __shfl_xor(mt, 16, 64));
  mt = fmaxf(mt, __shfl_xor(mt, 32, 64));
  float mnew = fmaxf(m, mt);
  float sf = __builtin_amdgcn_exp2f(m - mnew);
  m = mnew;
  float rs = 0.f;
#pragma unroll
  for (int nt = 0; nt < 4; ++nt)
#pragma unroll
    for (int rg = 0; rg < 4; ++rg) {
      float p = __builtin_amdgcn_exp2f(s4[nt][rg] - mnew);
      s4[nt][rg] = p;
      rs += p;
    }
  rs += __shfl_xor(rs, 16, 64);
  rs += __shfl_xor(rs, 32, 64);
  l = l * sf + rs;
#pragma unroll
  for (int nt = 0; nt < 4; ++nt) o[nt] *= sf;
  bf16x8 pf[2];
#pragma unroll
  for (int kc = 0; kc < 2; ++kc) {
    u32x4 w;
    w[0] = cvt_pk_bf16(s4[2 * kc][0], s4[2 * kc][1]);
    w[1] = cvt_pk_bf16(s4[2 * kc][2], s4[2 * kc][3]);
    w[2] = cvt_pk_bf16(s4[2 * kc + 1][0], s4[2 * kc + 1][1]);
    w[3] = cvt_pk_bf16(s4[2 * kc + 1][2], s4[2 * kc + 1][3]);
    pf[kc] = __builtin_bit_cast(bf16x8, w);
  }
#pragma unroll
  for (int nt2 = 0; nt2 < 4; ++nt2) {
    int d = nt2 * 16 + ql;
#pragma unroll
    for (int kc = 0; kc < 2; ++kc) {
      int sl = (kc * 4 + g) ^ (d & 7);
      bf16x8 vf = *(const bf16x8*)&Vc[d * 64 + sl * 8];
      o[nt2] = __builtin_amdgcn_mfma_f32_16x16x32_bf16(vf, pf[kc], o[nt2], 0, 0, 0);
    }
  }
}

__device__ __forceinline__ void attn_epi(const f32x4 o[4], float l,
                                         short* __restrict__ seqo, float* ep,
                                         int b, int h, int qt, int wave, int lane) {
  const int ql = lane & 15, g = lane >> 4;
  float inv = 1.f / l;
#pragma unroll
  for (int nt2 = 0; nt2 < 4; ++nt2) {
    f32x4 v = o[nt2] * inv;
    *(f32x4*)&ep[ql * 64 + (((nt2 * 4 + g) ^ (ql & 7)) << 2)] = v;
  }
  short* srow = seqo + ((size_t)b * 2048 + qt * 64 + wave * 16) * 1024 + h * 64;
#pragma unroll
  for (int p = 0; p < 8; ++p) {
    int prow = p * 2 + (lane >> 5);
    int d2 = (lane & 31) * 2;
    const float* rp = &ep[prow * 64 + (((d2 >> 2) ^ (prow & 7)) << 2) + (d2 & 3)];
    float2 vv = *(const float2*)rp;
    *(unsigned*)&srow[(size_t)prow * 1024 + d2] = cvt_pk_bf16(vv.x, vv.y);
  }
}

__global__ __launch_bounds__(512, 4) void k_attn(const short* __restrict__ Q,
                                                 const short* __restrict__ Kg,
                                                 const short* __restrict__ Vg,
                                                 short* __restrict__ seqo) {
  __shared__ short Kt[2][2][64 * 64];  // [half][buf]
  __shared__ short Vt[2][2][64 * 64];
  const int wg = blockIdx.x;
  const int x = wg & 7, s = wg >> 3;
  const int bh = 4 * x + (s >> 3);
  const int tid = threadIdx.x;
  const int half = tid >> 8;
  const int pi = ((s & 7) << 1) + half;
  const int qtA = pi, qtB = 31 - pi;
  const int b = bh >> 4, h = bh & 15;
  const int wave = (tid >> 6) & 3, lane = tid & 63;
  const int ql = lane & 15, g = lane >> 4;
  const short* qbase = Q + (size_t)bh * 2048 * 64;
  const int qgA = qtA * 64 + wave * 16 + ql;
  const int qgB = qtB * 64 + wave * 16 + ql;
  bf16x8 qaA[2], qaB[2];
  {
    const short* qr = qbase + (size_t)qgA * 64;
    qaA[0] = *(const bf16x8*)&qr[g * 8];
    qaA[1] = *(const bf16x8*)&qr[32 + g * 8];
    qr = qbase + (size_t)qgB * 64;
    qaB[0] = *(const bf16x8*)&qr[g * 8];
    qaB[1] = *(const bf16x8*)&qr[32 + g * 8];
  }
  f32x4 oA[4] = {}, oB[4] = {};
  float mA = -1e30f, lA = 0.f, mB = -1e30f, lB = 0.f;
  const short* kgb = Kg + (size_t)bh * 2048 * 64;
  const short* vgb = Vg + (size_t)bh * 64 * 2048;

  auto stage = [&](int buf, int kt) {
    int kv0 = kt * 64;
#pragma unroll
    for (int j = 0; j < 2; ++j) {
      int slot = (wave * 2 + j) * 64 + lane;
      int r = slot >> 3, s8 = slot & 7;
      int ss = s8 ^ (r & 7);
      load_lds16(kgb + (size_t)(kv0 + r) * 64 + ss * 8, &Kt[half][buf][slot * 8]);
      load_lds16(vgb + (size_t)r * 2048 + kv0 + ss * 8, &Vt[half][buf][slot * 8]);
    }
  };

  stage(0, 0);
  int cur = 0;
  for (int it = 0; it < 33; ++it) {
    __syncthreads();
    if (it < 32) {
      int nit = it + 1;
      int nkt2 = (nit <= qtB) ? nit : nit - qtB - 1;
      stage(cur ^ 1, nkt2);
    }
    const short* Kc = Kt[half][cur];
    const short* Vc = Vt[half][cur];
    if (it <= qtB)
      attn_core(qaB, oB, mB, lB, Kc, Vc, qtB, it, qgB, ql, g);
    else
      attn_core(qaA, oA, mA, lA, Kc, Vc, qtA, it - qtB - 1, qgA, ql, g);
    cur ^= 1;
  }
  __syncthreads();
  float* ep = (float*)&Kt[half][0][0] + wave * 1024;
  attn_epi(oB, lB, seqo, ep, b, h, qtB, wave, lane);
  attn_epi(oA, lA, seqo, ep, b, h, qtA, wave, lane);
}

// ---------------- Plücker lines: Csm [b,t,272] -> u=(wl@J)/|wl|, r=rl/|rl| ----------
__global__ __launch_bounds__(256) void k_lines(const float* __restrict__ Cs,
                                               const float* __restrict__ Jm,
                                               float* __restrict__ u,
                                               float* __restrict__ rr) {
  int idx = blockIdx.x * 256 + threadIdx.x;
  if (idx >= 2 * 2048 * 16) return;
  int h = idx & 15, t = (idx >> 4) & 2047, b = idx >> 15;
  const float* rowx = Cs + (size_t)(b * 2048 + t) * 272;
  float w1[4], w2[4], r1[4], r2[4];
  if (t == 0) {
#pragma unroll
    for (int i = 0; i < 4; ++i) w1[i] = 0.f;
  } else {
    const float* prev = Cs + (size_t)(b * 2048 + t - 1) * 272;
#pragma unroll
    for (int i = 0; i < 4; ++i) w1[i] = prev[h * 4 + i];
  }
#pragma unroll
  for (int i = 0; i < 4; ++i) {
    w2[i] = rowx[64 + h * 4 + i];
    r1[i] = rowx[128 + h * 4 + i];
    r2[i] = rowx[192 + h * 4 + i];
  }
  const int pi[6] = {0, 0, 0, 1, 1, 2}, pj[6] = {1, 2, 3, 2, 3, 3};
  float wl[6], rl[6], nw = 0.f, nr = 0.f;
#pragma unroll
  for (int e = 0; e < 6; ++e) {
    wl[e] = w1[pi[e]] * w2[pj[e]] - w1[pj[e]] * w2[pi[e]];
    rl[e] = r1[pi[e]] * r2[pj[e]] - r1[pj[e]] * r2[pi[e]];
    nw += wl[e] * wl[e];
    nr += rl[e] * rl[e];
  }
  nw = 1.f / fmaxf(sqrtf(nw), 1e-12f);
  nr = 1.f / fmaxf(sqrtf(nr), 1e-12f);
  size_t base = (((size_t)b * 16 + h) * 2048 + t) * 6;
#pragma unroll
  for (int jc = 0; jc < 6; ++jc) {
    float s = 0.f;
#pragma unroll
    for (int i = 0; i < 6; ++i) s += wl[i] * Jm[i * 6 + jc];
    u[base + jc] = s * nw;
    rr[base + jc] = rl[jc] * nr;
  }
}

// ------------- decayed prefix scan per channel: w[bh][ch][t] = S_t[p][q] -------------
__global__ __launch_bounds__(256) void k_scanw(const float* __restrict__ u,
                                               float* __restrict__ w,
                                               const float* __restrict__ decays) {
  __shared__ float wtot[4];
  const int ch = blockIdx.x;
  const int bh = blockIdx.y;
  const float d = decays[bh & 15];
  const int p = ch / 6, q = ch % 6;
  const int tid = threadIdx.x, lane = tid & 63, wv = tid >> 6;
  const float* ub = u + (size_t)bh * 2048 * 6;
  const int t0 = tid * 8;
  float z[8];
  float a = 0.f;
#pragma unroll
  for (int i = 0; i < 8; ++i) {
    float up = ub[(t0 + i) * 6 + p], uq = ub[(t0 + i) * 6 + q];
    z[i] = up * uq;
    a = d * (a + z[i]);
  }
  float d8 = d * d; d8 *= d8; d8 *= d8;
  float I = a;
  float ds = d8;
#pragma unroll
  for (int s = 1; s < 64; s <<= 1) {
    float v = __shfl_up(I, s, 64);
    if (lane >= s) I += ds * v;
    ds *= ds;
  }
  if (lane == 63) wtot[wv] = I;
  __syncthreads();
  float carry = 0.f;
  for (int w2 = 0; w2 < wv; ++w2) carry = carry * ds + wtot[w2];
  float dlp1 = exp2f(log2f(d8) * (float)(lane + 1));
  float Ig = I + dlp1 * carry;
  float E = __shfl_up(Ig, 1, 64);
  if (lane == 0) E = carry;
  float S = E;
  float out[8];
#pragma unroll
  for (int i = 0; i < 8; ++i) {
    out[i] = S;
    S = d * (S + z[i]);
  }
  float4* wp = (float4*)(w + ((size_t)bh * 36 + ch) * 2048 + t0);
  wp[0] = make_float4(out[0], out[1], out[2], out[3]);
  wp[1] = make_float4(out[4], out[5], out[6], out[7]);
}

// ------------- scores[bh][t] = sum_ch r[p]*r[q] * w[bh][ch][t] ----------------------
__global__ __launch_bounds__(256) void k_scandot(const float* __restrict__ rr,
                                                 const float* __restrict__ w,
                                                 float* __restrict__ scores) {
  const int bh = blockIdx.y;
  const int t = blockIdx.x * 256 + threadIdx.x;
  const float* rb = rr + ((size_t)bh * 2048 + t) * 6;
  float r[6];
#pragma unroll
  for (int i = 0; i < 6; ++i) r[i] = rb[i];
  const float* wb = w + (size_t)bh * 36 * 2048 + t;
  float acc = 0.f;
#pragma unroll
  for (int ch = 0; ch < 36; ++ch)
    acc += r[ch / 6] * r[ch % 6] * wb[(size_t)ch * 2048];
  scores[(size_t)bh * 2048 + t] = acc;
}

// ---------------- gate: gmean[b,t] = mean_h sig(score*scale_h)*sig(memg) -----------
__global__ __launch_bounds__(256) void k_gate(const float* __restrict__ scores,
                                              const float* __restrict__ Cs,
                                              const float* __restrict__ memg_b,
                                              const float* __restrict__ mem_scale,
                                              float* __restrict__ gmean) {
  int idx = blockIdx.x * 256 + threadIdx.x;
  if (idx >= BT) return;
  int b = idx >> 11, t = idx & 2047;
  float acc = 0.f;
#pragma unroll
  for (int h = 0; h < 16; ++h) {
    float s = scores[((size_t)(b * 16 + h) * 2048) + t];
    float gl = Cs[(size_t)idx * 272 + 256 + h] + memg_b[h];
    float a = 1.f / (1.f + __expf(-s * mem_scale[h]));
    float gg = 1.f / (1.f + __expf(-gl));
    acc += a * gg;
  }
  gmean[idx] = acc * (1.f / 16.f);
}

// ---------------- fuse: Fb = bf16(seq_bf16 + gmean*memval_bf16) ----------------
__global__ __launch_bounds__(256) void k_fuse(const short* __restrict__ s,
                                              const short* __restrict__ mv,
                                              const float* __restrict__ gm,
                                              short* __restrict__ dst, int n4) {
  int i = blockIdx.x * 256 + threadIdx.x;
  if (i >= n4) return;
  float gg = gm[i >> 8];
  short4 a = ((const short4*)s)[i];
  short4 m = ((const short4*)mv)[i];
  short4 o;
  o.x = f2bf(bf2f(a.x) + gg * bf2f(m.x));
  o.y = f2bf(bf2f(a.y) + gg * bf2f(m.y));
  o.z = f2bf(bf2f(a.z) + gg * bf2f(m.z));
  o.w = f2bf(bf2f(a.w) + gg * bf2f(m.w));
  ((short4*)dst)[i] = o;
}

extern "C" void kernel_launch(void* const* d_in, const int* in_sizes, int n_in,
                              void* d_out, int out_size, void* d_ws, size_t ws_size,
                              hipStream_t stream) {
  const float* x = (const float*)d_in[0];
  const float* qkv_w = (const float*)d_in[1];
  const float* qkv_b = (const float*)d_in[2];
  const float* w1w = (const float*)d_in[3];
  const float* w2w = (const float*)d_in[4];
  const float* w1r = (const float*)d_in[5];
  const float* w2r = (const float*)d_in[6];
  const float* memv_w = (const float*)d_in[7];
  const float* memv_b = (const float*)d_in[8];
  const float* memg_w = (const float*)d_in[9];
  const float* memg_b = (const float*)d_in[10];
  const float* mem_scale = (const float*)d_in[11];
  const float* out_w = (const float*)d_in[12];
  const float* out_b = (const float*)d_in[13];
  const float* Jm = (const float*)d_in[14];
  const float* decays = (const float*)d_in[15];

  char* w = (char*)d_ws;
  size_t off = 0;
  auto alloc = [&](size_t bytes) -> void* {
    void* p = w + off;
    off += (bytes + 255) & ~(size_t)255;
    return p;
  };
  short* xb = (short*)alloc((size_t)BT * Dd * 2);
  short* WTall = (short*)alloc((size_t)4096 * 1024 * 2);  // qkv(3072)|memv(1024)
  short* WTsm = (short*)alloc((size_t)384 * 1024 * 2);    // w1|w2|r1|r2|memg
  short* WTout = (short*)alloc((size_t)1024 * 1024 * 2);
  short* qb = (short*)alloc((size_t)32 * 2048 * 64 * 2);
  short* kb = (short*)alloc((size_t)32 * 2048 * 64 * 2);
  short* vtmp = (short*)alloc((size_t)BT * 1024 * 2);
  short* vb = (short*)alloc((size_t)32 * 64 * 2048 * 2);
  float* Csm = (float*)alloc((size_t)BT * 272 * 4);
  float* ua = (float*)alloc((size_t)32 * 2048 * 6 * 4);
  float* ra = (float*)alloc((size_t)32 * 2048 * 6 * 4);
  float* sc = (float*)alloc((size_t)32 * 2048 * 4);
  float* gm = (float*)alloc((size_t)BT * 4);
  short* mvb = (short*)alloc((size_t)BT * 1024 * 2);
  short* seqo = (short*)alloc((size_t)BT * 1024 * 2);
  short* Fb = (short*)alloc((size_t)BT * Dd * 2);
  float* wscan = (float*)qb;  // aliases qb+kb, dead after k_attn
  (void)ws_size; (void)in_sizes; (void)n_in; (void)out_size;

  // prep
  k_cvt<<<(BT * Dd / 4 + 255) / 256, 256, 0, stream>>>(x, xb, BT * Dd / 4);
  k_wt2<<<dim3(48, 16), 256, 0, stream>>>(qkv_w, WTall, 1024, 3072);
  k_wt2<<<dim3(16, 16), 256, 0, stream>>>(memv_w, WTall + (size_t)3072 * 1024, 1024, 1024);
  k_wt5<<<dim3(1, 16, 5), 256, 0, stream>>>(w1w, w2w, w1r, w2r, memg_w, WTsm);
  k_wt2<<<dim3(16, 16), 256, 0, stream>>>(out_w, WTout, 1024, 1024);

  // fused 256^2 8-phase GEMM: qkv (3072) | memv (1024, ->bf16) over N=4096, grid=256
  k_g256<<<256, 512, 0, stream>>>(xb, WTall, qkv_b, nullptr, memv_b,
                                  qb, kb, vtmp, mvb, 1024, 0, 1);
  // sm projections (N=272, padded B to 384)
  k_gemm<<<dim3(3, 64), 256, 0, stream>>>(xb, WTsm, nullptr, Csm, 1024, 272, 272);

  k_vtrans<<<dim3(32, 32), 256, 0, stream>>>(vtmp, vb);

  // attention: 256 balanced blocks x 512 threads
  k_attn<<<256, 512, 0, stream>>>(qb, kb, vb, seqo);

  // memory path
  k_lines<<<(2 * 2048 * 16 + 255) / 256, 256, 0, stream>>>(Csm, Jm, ua, ra);
  k_scanw<<<dim3(36, 32), 256, 0, stream>>>(ua, wscan, decays);
  k_scandot<<<dim3(8, 32), 256, 0, stream>>>(ra, wscan, sc);
  k_gate<<<(BT + 255) / 256, 256, 0, stream>>>(sc, Csm, memg_b, mem_scale, gm);

  // fuse + final 256^2 GEMM (N=1024, grid 16x4)
  k_fuse<<<(BT * Dd / 4 + 255) / 256, 256, 0, stream>>>(seqo, mvb, gm, Fb, BT * Dd / 4);
  k_g256<<<64, 512, 0, stream>>>(Fb, WTout, out_b, (float*)d_out, nullptr,
                                 nullptr, nullptr, nullptr, nullptr, 1024, 1024, 0);
}

// Round 11
// 220.567 us; speedup vs baseline: 1.0675x; 1.0589x over previous
//
#include <hip/hip_runtime.h>

#define BT 4096      // B*T
#define Dd 1024
#define Tt 2048

typedef __attribute__((ext_vector_type(8))) short bf16x8;
typedef __attribute__((ext_vector_type(4))) float f32x4;
typedef __attribute__((ext_vector_type(4))) unsigned u32x4;

__device__ __forceinline__ short f2bf(float f) {
  unsigned u = __builtin_bit_cast(unsigned, f);
  u = (u + 0x7FFFu + ((u >> 16) & 1u)) >> 16;
  return (short)u;
}
__device__ __forceinline__ float bf2f(short s) {
  unsigned u = ((unsigned)(unsigned short)s) << 16;
  return __builtin_bit_cast(float, u);
}
__device__ __forceinline__ unsigned cvt_pk_bf16(float a, float b) {
  unsigned r;
  asm("v_cvt_pk_bf16_f32 %0, %1, %2" : "=v"(r) : "v"(a), "v"(b));
  return r;
}

__device__ __forceinline__ void load_lds16(const void* gsrc, void* ldst) {
  __builtin_amdgcn_global_load_lds(
      (const __attribute__((address_space(1))) void*)gsrc,
      (__attribute__((address_space(3))) void*)ldst, 16, 0, 0);
}

// ---------------- x fp32 -> bf16 ----------------
__global__ __launch_bounds__(256) void k_cvt(const float* __restrict__ src,
                                             short* __restrict__ dst, int n4) {
  int i = blockIdx.x * 256 + threadIdx.x;
  if (i >= n4) return;
  float4 v = ((const float4*)src)[i];
  short4 o;
  o.x = f2bf(v.x); o.y = f2bf(v.y); o.z = f2bf(v.z); o.w = f2bf(v.w);
  ((short4*)dst)[i] = o;
}

// ------------- tiled weight transpose: src [K][N] f32 -> dst [N][K] bf16 -------------
__global__ __launch_bounds__(256) void k_wt2(const float* __restrict__ src,
                                             short* __restrict__ dst, int K, int N) {
  __shared__ float tile[64][65];
  const int n0 = blockIdx.x * 64, k0 = blockIdx.y * 64;
  const int c = threadIdx.x & 63, r4 = threadIdx.x >> 6;
#pragma unroll
  for (int i = 0; i < 16; ++i) {
    int r = i * 4 + r4;
    float v = 0.f;
    if (k0 + r < K && n0 + c < N) v = src[(size_t)(k0 + r) * N + n0 + c];
    tile[r][c] = v;
  }
  __syncthreads();
#pragma unroll
  for (int i = 0; i < 16; ++i) {
    int n = i * 4 + r4;
    if (n0 + n < N && k0 + c < K)
      dst[(size_t)(n0 + n) * K + k0 + c] = f2bf(tile[c][n]);
  }
}

// ------- batched small transposes into WTsm rows z*64.. (w1w,w2w,w1r,w2r,memg) ------
__global__ __launch_bounds__(256) void k_wt5(const float* __restrict__ s0,
                                             const float* __restrict__ s1,
                                             const float* __restrict__ s2,
                                             const float* __restrict__ s3,
                                             const float* __restrict__ s4,
                                             short* __restrict__ dst) {
  __shared__ float tile[64][65];
  const int z = blockIdx.z;
  const float* src = z == 0 ? s0 : z == 1 ? s1 : z == 2 ? s2 : z == 3 ? s3 : s4;
  const int N = (z == 4) ? 16 : 64;
  const int rowoff = z * 64;
  const int k0 = blockIdx.y * 64;
  const int c = threadIdx.x & 63, r4 = threadIdx.x >> 6;
#pragma unroll
  for (int i = 0; i < 16; ++i) {
    int r = i * 4 + r4;
    float v = 0.f;
    if (c < N) v = src[(size_t)(k0 + r) * N + c];
    tile[r][c] = v;
  }
  __syncthreads();
#pragma unroll
  for (int i = 0; i < 16; ++i) {
    int n = i * 4 + r4;
    if (n < N)
      dst[(size_t)(rowoff + n) * 1024 + k0 + c] = f2bf(tile[c][n]);
  }
}

// ====== 256x256 8-phase GEMM — serpentine quadrants + reg reuse + sched pins =======
// Regions (16KB): A(d,h)=bytes (d*2+h)*16384, rows h=mq bit; B(d,h)=65536+(d*2+h)*16384.
// Serpentine (0,0)->(0,1)->(1,1)->(1,0): A held 2 phases, B0 held in regs ph1->ph4.
// LDS reads/K-tile/wave: 8A+4B, 4B, 8A, 0 = 24 b128 (was 48).
// Stage targets (write-safety vs last LDS read): ph1 A'(h1,kt+1) [other dbuf], ph2
// B'(h1,kt+1), ph3 A(h0,kt+2) [A0 last read ph1], ph4 B(h0,kt+2) [B0 last read ph1].
// vmcnt(4) at ph4 only (12 outstanding -> kt+1 fully landed). Verified r9 numerics.
// mode 1: fused routing qkv|memv->bf16.  mode 2: split-K/4 fp32 partials.
__global__ __launch_bounds__(512, 2) void k_g256(
    const short* __restrict__ A, const short* __restrict__ Bt,
    const float* __restrict__ bias,
    const float* __restrict__ bias2,
    short* __restrict__ oq, short* __restrict__ ok_, short* __restrict__ ov,
    short* __restrict__ omv, int K, int mode) {
  __shared__ __align__(16) short lds[65536];  // 128 KiB
  const int tid = threadIdx.x;
  const int wid = tid >> 6, lane = tid & 63;
  const int wr = wid >> 2, wc = wid & 3;      // 2M x 4N waves
  const int ql = lane & 15, g = lane >> 4;
  int m_t, n_t, nkt, ks = 0;
  if (mode == 1) {  // 256 blocks, XCD-chunked
    int wg = blockIdx.x, xcd = wg & 7, idx = wg >> 3;
    m_t = xcd * 2 + (idx >> 4);
    n_t = idx & 15;
    nkt = K >> 6;
  } else {          // mode 2: split-K/4. 256 blocks = ks(4) x m(16) x n(4)
    ks = blockIdx.x >> 6;
    int r = blockIdx.x & 63;
    m_t = r >> 2;
    n_t = r & 3;
    nkt = (K >> 2) >> 6;  // 4 K-tiles
  }
  const int bm = m_t * 256, bn = n_t * 256;
  const short* Abase = A + ks * (K >> 2);
  const short* Bbase = Bt + ks * (K >> 2);
  f32x4 acc[8][4] = {};

  // ---- hoisted stage addressing ----
  const short* srcA[2][2];
  const short* srcB[2][2];
  short* dstA[2];
  short* dstB[2];
#pragma unroll
  for (int j = 0; j < 2; ++j) {
    int o16 = j * 512 + tid;
    int rr = o16 >> 3, s = o16 & 7;
    int sp = s ^ (rr & 7);
#pragma unroll
    for (int h = 0; h < 2; ++h) {
      int growA = ((rr >> 6) << 7) + h * 64 + (rr & 63);
      int growB = ((rr >> 5) << 6) + h * 32 + (rr & 31);
      srcA[h][j] = Abase + (size_t)(bm + growA) * K + sp * 8;
      srcB[h][j] = Bbase + (size_t)(bn + growB) * K + sp * 8;
    }
    dstA[j] = lds + o16 * 8;
    dstB[j] = lds + 32768 + o16 * 8;
  }
#define STG_A(H, DP, KT)                                                      \
  do {                                                                        \
    load_lds16(srcA[H][0] + ((KT) << 6), dstA[0] + ((DP)*2 + (H)) * 8192);    \
    load_lds16(srcA[H][1] + ((KT) << 6), dstA[1] + ((DP)*2 + (H)) * 8192);    \
  } while (0)
#define STG_B(H, DP, KT)                                                      \
  do {                                                                        \
    load_lds16(srcB[H][0] + ((KT) << 6), dstB[0] + ((DP)*2 + (H)) * 8192);    \
    load_lds16(srcB[H][1] + ((KT) << 6), dstB[1] + ((DP)*2 + (H)) * 8192);    \
  } while (0)

  // ---- hoisted read bases (swizzle folded) ----
  const int q7 = ql & 7;
  const char* baseA0 = (const char*)lds + wr * 8192 + ql * 128 + ((g ^ q7) << 4);
  const char* baseA1 = (const char*)lds + wr * 8192 + ql * 128 + (((g + 4) ^ q7) << 4);
  const char* baseB0 =
      (const char*)lds + 65536 + wc * 4096 + ql * 128 + ((g ^ q7) << 4);
  const char* baseB1 =
      (const char*)lds + 65536 + wc * 4096 + ql * 128 + (((g + 4) ^ q7) << 4);

#define RD_A(DST, DOFF, MQ)                                                    \
  _Pragma("unroll") for (int mi = 0; mi < 4; ++mi) {                           \
    DST[mi][0] = *(const bf16x8*)(baseA0 + (DOFF) + (MQ)*16384 + mi * 2048);   \
    DST[mi][1] = *(const bf16x8*)(baseA1 + (DOFF) + (MQ)*16384 + mi * 2048);   \
  }
#define RD_B(DST, DOFF, NQ)                                                    \
  _Pragma("unroll") for (int ni = 0; ni < 2; ++ni) {                           \
    DST[ni][0] = *(const bf16x8*)(baseB0 + (DOFF) + (NQ)*16384 + ni * 2048);   \
    DST[ni][1] = *(const bf16x8*)(baseB1 + (DOFF) + (NQ)*16384 + ni * 2048);   \
  }
#define MFMA16(AF, BF, MQ, NQ)                                                 \
  do {                                                                         \
    __builtin_amdgcn_s_setprio(1);                                             \
    _Pragma("unroll") for (int kh = 0; kh < 2; ++kh)                           \
        _Pragma("unroll") for (int mi = 0; mi < 4; ++mi)                       \
            _Pragma("unroll") for (int ni = 0; ni < 2; ++ni)                   \
                acc[(MQ)*4 + mi][(NQ)*2 + ni] =                                \
        __builtin_amdgcn_mfma_f32_16x16x32_bf16(                               \
            BF[ni][kh], AF[mi][kh], acc[(MQ)*4 + mi][(NQ)*2 + ni], 0, 0, 0);   \
    __builtin_amdgcn_s_setprio(0);                                             \
  } while (0)
#define BAR_LG                                                                 \
  __builtin_amdgcn_sched_barrier(0);                                           \
  __builtin_amdgcn_s_barrier();                                                \
  asm volatile("s_waitcnt lgkmcnt(0)" ::: "memory");                           \
  __builtin_amdgcn_sched_barrier(0)
#define BAR_ONLY                                                               \
  __builtin_amdgcn_sched_barrier(0);                                           \
  __builtin_amdgcn_s_barrier();                                                \
  __builtin_amdgcn_sched_barrier(0)

  // prologue: kt0 full + kt1 {A.h0, B.h0}
  STG_A(0, 0, 0); STG_B(0, 0, 0); STG_A(1, 0, 0); STG_B(1, 0, 0);
  STG_A(0, 1, 1); STG_B(0, 1, 1);
  asm volatile("s_waitcnt vmcnt(4)" ::: "memory");
  __builtin_amdgcn_s_barrier();

  for (int kt = 0; kt < nkt; ++kt) {
    const int dOff = (kt & 1) << 15;
    const int dn = (kt + 1) & 1, dn2 = (kt + 2) & 1;
    const bool s1 = kt + 1 < nkt, s2 = kt + 2 < nkt;
    bf16x8 af[4][2], b0[2][2], b1[2][2];
    // phase 1: (0,0)
    RD_A(af, dOff, 0);
    RD_B(b0, dOff, 0);
    if (s1) STG_A(1, dn, kt + 1);
    BAR_LG;
    MFMA16(af, b0, 0, 0);
    BAR_ONLY;
    // phase 2: (0,1) — A reused
    RD_B(b1, dOff, 1);
    if (s1) STG_B(1, dn, kt + 1);
    BAR_LG;
    MFMA16(af, b1, 0, 1);
    BAR_ONLY;
    // phase 3: (1,1) — B1 reused
    RD_A(af, dOff, 1);
    if (s2) STG_A(0, dn2, kt + 2);
    BAR_LG;
    MFMA16(af, b1, 1, 1);
    BAR_ONLY;
    // phase 4: (1,0) — no LDS reads (A1, B0 in regs)
    if (s2) STG_B(0, dn2, kt + 2);
    BAR_ONLY;
    MFMA16(af, b0, 1, 0);
    if (s2) asm volatile("s_waitcnt vmcnt(4)" ::: "memory");
    else    asm volatile("s_waitcnt vmcnt(0)" ::: "memory");
    BAR_ONLY;
  }
#undef BAR_LG
#undef BAR_ONLY
#undef MFMA16
#undef RD_A
#undef RD_B
#undef STG_A
#undef STG_B

  // epilogue
#pragma unroll
  for (int a = 0; a < 8; ++a) {
    const int m = bm + wr * 128 + a * 16 + ql;
    const int b = m >> 11, t = m & 2047;
#pragma unroll
    for (int c = 0; c < 4; ++c) {
      const int n0 = bn + wc * 64 + c * 16 + g * 4;
      f32x4 v = acc[a][c];
      if (mode == 2) {
        float* part = (float*)(ks == 0 ? (void*)oq : ks == 1 ? (void*)ok_
                               : ks == 2 ? (void*)ov : (void*)omv);
        *(f32x4*)&part[(size_t)m * 1024 + n0] = v;
      } else {
        if (n0 < 3072) {
          const float4 b4 = *(const float4*)&bias[n0];
          v[0] += b4.x; v[1] += b4.y; v[2] += b4.z; v[3] += b4.w;
          uint2 pk = make_uint2(cvt_pk_bf16(v[0], v[1]), cvt_pk_bf16(v[2], v[3]));
          const int sel = n0 >> 10, rem = n0 & 1023;
          if (sel == 0)
            *(uint2*)&oq[((size_t)(b * 16 + (rem >> 6)) * 2048 + t) * 64 + (rem & 63)] = pk;
          else if (sel == 1)
            *(uint2*)&ok_[((size_t)(b * 16 + (rem >> 6)) * 2048 + t) * 64 + (rem & 63)] = pk;
          else
            *(uint2*)&ov[(size_t)(b * 2048 + t) * 1024 + rem] = pk;
        } else {
          const float4 b4 = *(const float4*)&bias2[n0 - 3072];
          v[0] += b4.x; v[1] += b4.y; v[2] += b4.z; v[3] += b4.w;
          uint2 pk = make_uint2(cvt_pk_bf16(v[0], v[1]), cvt_pk_bf16(v[2], v[3]));
          *(uint2*)&omv[(size_t)(b * 2048 + t) * 1024 + n0 - 3072] = pk;
        }
      }
    }
  }
}

// -------- split-K reduce: out = p0+p1+p2+p3 + bias (per-column) ---------------------
__global__ __launch_bounds__(256) void k_red(const float* __restrict__ p0,
                                             const float* __restrict__ p1,
                                             const float* __restrict__ p2,
                                             const float* __restrict__ p3,
                                             const float* __restrict__ bias,
                                             float* __restrict__ out) {
  int i = blockIdx.x * 256 + threadIdx.x;  // float4 index over 4096*1024/4
  float4 a = ((const float4*)p0)[i];
  float4 b = ((const float4*)p1)[i];
  float4 c = ((const float4*)p2)[i];
  float4 d = ((const float4*)p3)[i];
  float4 bi = ((const float4*)bias)[i & 255];
  float4 o;
  o.x = a.x + b.x + c.x + d.x + bi.x;
  o.y = a.y + b.y + c.y + d.y + bi.y;
  o.z = a.z + b.z + c.z + d.z + bi.z;
  o.w = a.w + b.w + c.w + d.w + bi.w;
  ((float4*)out)[i] = o;
}

// ---- 64x128 GEMM (r7 structure) — used for the small sm projection only ------------
__global__ __launch_bounds__(256) void k_gemm(
    const short* __restrict__ A, const short* __restrict__ Bt,
    const float* __restrict__ bias, float* __restrict__ C,
    int K, int ldc, int ncap) {
  __shared__ short As[3][64 * 32];
  __shared__ short Bs[3][128 * 32];
  const int tid = threadIdx.x;
  const int wave = tid >> 6, lane = tid & 63;
  const int wg = blockIdx.y * gridDim.x + blockIdx.x;
  const int xcd = wg & 7, idx = wg >> 3;
  const int m_t = xcd * (gridDim.y >> 3) + idx / gridDim.x;
  const int n_t = idx % gridDim.x;
  const int bm = m_t * 64, bn = n_t * 128;
  const int mh = (wave >> 1) * 32, nh = (wave & 1) * 64;
  const int ql = lane & 15, g = lane >> 4;
  f32x4 acc[2][4] = {};
  const int kTiles = K >> 5;

  const short *agA, *agB0, *agB1;
  short *ldA, *ldB0, *ldB1;
  {
    int slot = wave * 64 + lane;
    int r = slot >> 2, u = slot & 3;
    int c = (u + 4 - ((r >> 1) & 3)) & 3;
    agA = A + (size_t)(bm + r) * K + c * 8;
    ldA = (short*)&As[0][slot * 8];
    slot = wave * 2 * 64 + lane;
    r = slot >> 2; u = slot & 3;
    c = (u + 4 - ((r >> 1) & 3)) & 3;
    agB0 = Bt + (size_t)(bn + r) * K + c * 8;
    ldB0 = (short*)&Bs[0][slot * 8];
    slot = (wave * 2 + 1) * 64 + lane;
    r = slot >> 2; u = slot & 3;
    c = (u + 4 - ((r >> 1) & 3)) & 3;
    agB1 = Bt + (size_t)(bn + r) * K + c * 8;
    ldB1 = (short*)&Bs[0][slot * 8];
  }
  const int bufStride = 64 * 32, bufStrideB = 128 * 32;
  auto stage = [&](int buf, int kt) {
    const int k0 = kt << 5;
    load_lds16(agA + k0, ldA + buf * bufStride);
    load_lds16(agB0 + k0, ldB0 + buf * bufStrideB);
    load_lds16(agB1 + k0, ldB1 + buf * bufStrideB);
  };
  stage(0, 0);
  stage(1, 1);
  int cur = 0;
  for (int kt = 0; kt < kTiles; ++kt) {
    if (kt + 1 < kTiles)
      asm volatile("s_waitcnt vmcnt(3)\n\ts_barrier" ::: "memory");
    else
      asm volatile("s_waitcnt vmcnt(0)\n\ts_barrier" ::: "memory");
    if (kt + 2 < kTiles) {
      int b2 = cur + 2; if (b2 >= 3) b2 -= 3;
      stage(b2, kt + 2);
    }
    bf16x8 af[2], bfr[4];
#pragma unroll
    for (int mi = 0; mi < 2; ++mi) {
      int row = mh + mi * 16 + ql;
      int ph = (g + (row >> 1)) & 3;
      af[mi] = *(const bf16x8*)&As[cur][row * 32 + ph * 8];
    }
#pragma unroll
    for (int ni = 0; ni < 4; ++ni) {
      int row = nh + ni * 16 + ql;
      int ph = (g + (row >> 1)) & 3;
      bfr[ni] = *(const bf16x8*)&Bs[cur][row * 32 + ph * 8];
    }
    __builtin_amdgcn_s_setprio(1);
#pragma unroll
    for (int mi = 0; mi < 2; ++mi)
#pragma unroll
      for (int ni = 0; ni < 4; ++ni)
        acc[mi][ni] = __builtin_amdgcn_mfma_f32_16x16x32_bf16(bfr[ni], af[mi],
                                                              acc[mi][ni], 0, 0, 0);
    __builtin_amdgcn_s_setprio(0);
    cur = (cur + 1 == 3) ? 0 : cur + 1;
  }
#pragma unroll
  for (int mi = 0; mi < 2; ++mi) {
    const int m = bm + mh + mi * 16 + ql;
#pragma unroll
    for (int ni = 0; ni < 4; ++ni) {
      const int n0 = bn + nh + ni * 16 + g * 4;
      if (n0 >= ncap) continue;
      f32x4 v = acc[mi][ni];
      if (bias) {
        const float4 b4 = *(const float4*)&bias[n0];
        v[0] += b4.x; v[1] += b4.y; v[2] += b4.z; v[3] += b4.w;
      }
      *(f32x4*)&C[(size_t)m * ldc + n0] = v;
    }
  }
}

// -------- V transpose + PV k-permute: vtmp [b,t,(h,dh)] -> vb [b,h,dh,tau(t)] --------
__global__ __launch_bounds__(256) void k_vtrans(const short* __restrict__ vtmp,
                                                short* __restrict__ vb) {
  __shared__ short tile[64][68];
  const int bh = blockIdx.x, b = bh >> 4, h = bh & 15;
  const int t0 = blockIdx.y * 64;
  const int tid = threadIdx.x;
#pragma unroll
  for (int pass = 0; pass < 16; ++pass) {
    int r = pass * 4 + (tid >> 6);
    int c = tid & 63;
    tile[r][c] = vtmp[((size_t)(b * 2048) + t0 + r) * 1024 + h * 64 + c];
  }
  __syncthreads();
#pragma unroll
  for (int pass = 0; pass < 16; ++pass) {
    int r = pass * 4 + (tid >> 6);  // dh
    int c = tid & 63;               // t offset within tile
    int cp = (c & 32) | (((c >> 2) & 3) << 3) | (((c >> 4) & 1) << 2) | (c & 3);
    vb[(((size_t)b * 16 + h) * 64 + r) * 2048 + t0 + cp] = tile[c][r];
  }
}

// ---------------- causal flash attention, swapped-operand, balanced pairs -----------
#define ATT_SCALE 0.18033688f  // 0.125 * log2(e)

__device__ __forceinline__ void attn_core(const bf16x8 qa[2], f32x4 o[4],
                                          float& m, float& l,
                                          const short* __restrict__ Kc,
                                          const short* __restrict__ Vc,
                                          int qt, int kt, int qglob,
                                          int ql, int g) {
  const int kv0 = kt * 64;
  f32x4 s4[4];
#pragma unroll
  for (int nt = 0; nt < 4; ++nt) {
    int krow = nt * 16 + ql;
    f32x4 s = {0.f, 0.f, 0.f, 0.f};
#pragma unroll
    for (int kc = 0; kc < 2; ++kc) {
      int sl = (kc * 4 + g) ^ (krow & 7);
      bf16x8 af = *(const bf16x8*)&Kc[krow * 64 + sl * 8];
      s = __builtin_amdgcn_mfma_f32_16x16x32_bf16(af, qa[kc], s, 0, 0, 0);
    }
    s4[nt] = s;
  }
  float mt = -1e30f;
  const bool diag = (kt == qt);
#pragma unroll
  for (int nt = 0; nt < 4; ++nt)
#pragma unroll
    for (int rg = 0; rg < 4; ++rg) {
      float v = s4[nt][rg] * ATT_SCALE;
      if (diag) {
        int kk = kv0 + nt * 16 + g * 4 + rg;
        v = (kk <= qglob) ? v : -1e30f;
      }
      s4[nt][rg] = v;
      mt = fmaxf(mt, v);
    }
  mt = fmaxf(mt, __shfl_xor(mt, 16, 64));
  mt = fmaxf(mt, __shfl_xor(mt, 32, 64));
  float mnew = fmaxf(m, mt);
  float sf = __builtin_amdgcn_exp2f(m - mnew);
  m = mnew;
  float rs = 0.f;
#pragma unroll
  for (int nt = 0; nt < 4; ++nt)
#pragma unroll
    for (int rg = 0; rg < 4; ++rg) {
      float p = __builtin_amdgcn_exp2f(s4[nt][rg] - mnew);
      s4[nt][rg] = p;
      rs += p;
    }
  rs += __shfl_xor(rs, 16, 64);
  rs += __shfl_xor(rs, 32, 64);
  l = l * sf + rs;
#pragma unroll
  for (int nt = 0; nt < 4; ++nt) o[nt] *= sf;
  bf16x8 pf[2];
#pragma unroll
  for (int kc = 0; kc < 2; ++kc) {
    u32x4 w;
    w[0] = cvt_pk_bf16(s4[2 * kc][0], s4[2 * kc][1]);
    w[1] = cvt_pk_bf16(s4[2 * kc][2], s4[2 * kc][3]);
    w[2] = cvt_pk_bf16(s4[2 * kc + 1][0], s4[2 * kc + 1][1]);
    w[3] = cvt_pk_bf16(s4[2 * kc + 1][2], s4[2 * kc + 1][3]);
    pf[kc] = __builtin_bit_cast(bf16x8, w);
  }
#pragma unroll
  for (int nt2 = 0; nt2 < 4; ++nt2) {
    int d = nt2 * 16 + ql;
#pragma unroll
    for (int kc = 0; kc < 2; ++kc) {
      int sl = (kc * 4 + g) ^ (d & 7);
      bf16x8 vf = *(const bf16x8*)&Vc[d * 64 + sl * 8];
      o[nt2] = __builtin_amdgcn_mfma_f32_16x16x32_bf16(vf, pf[kc], o[nt2], 0, 0, 0);
    }
  }
}

__device__ __forceinline__ void attn_epi(const f32x4 o[4], float l,
                                         short* __restrict__ seqo, float* ep,
                                         int b, int h, int qt, int wave, int lane) {
  const int ql = lane & 15, g = lane >> 4;
  float inv = 1.f / l;
#pragma unroll
  for (int nt2 = 0; nt2 < 4; ++nt2) {
    f32x4 v = o[nt2] * inv;
    *(f32x4*)&ep[ql * 64 + (((nt2 * 4 + g) ^ (ql & 7)) << 2)] = v;
  }
  short* srow = seqo + ((size_t)b * 2048 + qt * 64 + wave * 16) * 1024 + h * 64;
#pragma unroll
  for (int p = 0; p < 8; ++p) {
    int prow = p * 2 + (lane >> 5);
    int d2 = (lane & 31) * 2;
    const float* rp = &ep[prow * 64 + (((d2 >> 2) ^ (prow & 7)) << 2) + (d2 & 3)];
    float2 vv = *(const float2*)rp;
    *(unsigned*)&srow[(size_t)prow * 1024 + d2] = cvt_pk_bf16(vv.x, vv.y);
  }
}

__global__ __launch_bounds__(512, 4) void k_attn(const short* __restrict__ Q,
                                                 const short* __restrict__ Kg,
                                                 const short* __restrict__ Vg,
                                                 short* __restrict__ seqo) {
  __shared__ short Kt[2][2][64 * 64];  // [half][buf]
  __shared__ short Vt[2][2][64 * 64];
  const int wg = blockIdx.x;
  const int x = wg & 7, s = wg >> 3;
  const int bh = 4 * x + (s >> 3);
  const int tid = threadIdx.x;
  const int half = tid >> 8;
  const int pi = ((s & 7) << 1) + half;
  const int qtA = pi, qtB = 31 - pi;
  const int b = bh >> 4, h = bh & 15;
  const int wave = (tid >> 6) & 3, lane = tid & 63;
  const int ql = lane & 15, g = lane >> 4;
  const short* qbase = Q + (size_t)bh * 2048 * 64;
  const int qgA = qtA * 64 + wave * 16 + ql;
  const int qgB = qtB * 64 + wave * 16 + ql;
  bf16x8 qaA[2], qaB[2];
  {
    const short* qr = qbase + (size_t)qgA * 64;
    qaA[0] = *(const bf16x8*)&qr[g * 8];
    qaA[1] = *(const bf16x8*)&qr[32 + g * 8];
    qr = qbase + (size_t)qgB * 64;
    qaB[0] = *(const bf16x8*)&qr[g * 8];
    qaB[1] = *(const bf16x8*)&qr[32 + g * 8];
  }
  f32x4 oA[4] = {}, oB[4] = {};
  float mA = -1e30f, lA = 0.f, mB = -1e30f, lB = 0.f;
  const short* kgb = Kg + (size_t)bh * 2048 * 64;
  const short* vgb = Vg + (size_t)bh * 64 * 2048;

  auto stage = [&](int buf, int kt) {
    int kv0 = kt * 64;
#pragma unroll
    for (int j = 0; j < 2; ++j) {
      int slot = (wave * 2 + j) * 64 + lane;
      int r = slot >> 3, s8 = slot & 7;
      int ss = s8 ^ (r & 7);
      load_lds16(kgb + (size_t)(kv0 + r) * 64 + ss * 8, &Kt[half][buf][slot * 8]);
      load_lds16(vgb + (size_t)r * 2048 + kv0 + ss * 8, &Vt[half][buf][slot * 8]);
    }
  };

  stage(0, 0);
  int cur = 0;
  for (int it = 0; it < 33; ++it) {
    __syncthreads();
    if (it < 32) {
      int nit = it + 1;
      int nkt2 = (nit <= qtB) ? nit : nit - qtB - 1;
      stage(cur ^ 1, nkt2);
    }
    const short* Kc = Kt[half][cur];
    const short* Vc = Vt[half][cur];
    if (it <= qtB)
      attn_core(qaB, oB, mB, lB, Kc, Vc, qtB, it, qgB, ql, g);
    else
      attn_core(qaA, oA, mA, lA, Kc, Vc, qtA, it - qtB - 1, qgA, ql, g);
    cur ^= 1;
  }
  __syncthreads();
  float* ep = (float*)&Kt[half][0][0] + wave * 1024;
  attn_epi(oB, lB, seqo, ep, b, h, qtB, wave, lane);
  attn_epi(oA, lA, seqo, ep, b, h, qtA, wave, lane);
}

// ---------------- Plücker lines: Csm [b,t,272] -> u=(wl@J)/|wl|, r=rl/|rl| ----------
__global__ __launch_bounds__(256) void k_lines(const float* __restrict__ Cs,
                                               const float* __restrict__ Jm,
                                               float* __restrict__ u,
                                               float* __restrict__ rr) {
  int idx = blockIdx.x * 256 + threadIdx.x;
  if (idx >= 2 * 2048 * 16) return;
  int h = idx & 15, t = (idx >> 4) & 2047, b = idx >> 15;
  const float* rowx = Cs + (size_t)(b * 2048 + t) * 272;
  float w1[4], w2[4], r1[4], r2[4];
  if (t == 0) {
#pragma unroll
    for (int i = 0; i < 4; ++i) w1[i] = 0.f;
  } else {
    const float* prev = Cs + (size_t)(b * 2048 + t - 1) * 272;
#pragma unroll
    for (int i = 0; i < 4; ++i) w1[i] = prev[h * 4 + i];
  }
#pragma unroll
  for (int i = 0; i < 4; ++i) {
    w2[i] = rowx[64 + h * 4 + i];
    r1[i] = rowx[128 + h * 4 + i];
    r2[i] = rowx[192 + h * 4 + i];
  }
  const int pi[6] = {0, 0, 0, 1, 1, 2}, pj[6] = {1, 2, 3, 2, 3, 3};
  float wl[6], rl[6], nw = 0.f, nr = 0.f;
#pragma unroll
  for (int e = 0; e < 6; ++e) {
    wl[e] = w1[pi[e]] * w2[pj[e]] - w1[pj[e]] * w2[pi[e]];
    rl[e] = r1[pi[e]] * r2[pj[e]] - r1[pj[e]] * r2[pi[e]];
    nw += wl[e] * wl[e];
    nr += rl[e] * rl[e];
  }
  nw = 1.f / fmaxf(sqrtf(nw), 1e-12f);
  nr = 1.f / fmaxf(sqrtf(nr), 1e-12f);
  size_t base = (((size_t)b * 16 + h) * 2048 + t) * 6;
#pragma unroll
  for (int jc = 0; jc < 6; ++jc) {
    float s = 0.f;
#pragma unroll
    for (int i = 0; i < 6; ++i) s += wl[i] * Jm[i * 6 + jc];
    u[base + jc] = s * nw;
    rr[base + jc] = rl[jc] * nr;
  }
}

// ------------- decayed prefix scan per channel: w[bh][ch][t] = S_t[p][q] -------------
__global__ __launch_bounds__(256) void k_scanw(const float* __restrict__ u,
                                               float* __restrict__ w,
                                               const float* __restrict__ decays) {
  __shared__ float wtot[4];
  const int ch = blockIdx.x;
  const int bh = blockIdx.y;
  const float d = decays[bh & 15];
  const int p = ch / 6, q = ch % 6;
  const int tid = threadIdx.x, lane = tid & 63, wv = tid >> 6;
  const float* ub = u + (size_t)bh * 2048 * 6;
  const int t0 = tid * 8;
  float z[8];
  float a = 0.f;
#pragma unroll
  for (int i = 0; i < 8; ++i) {
    float up = ub[(t0 + i) * 6 + p], uq = ub[(t0 + i) * 6 + q];
    z[i] = up * uq;
    a = d * (a + z[i]);
  }
  float d8 = d * d; d8 *= d8; d8 *= d8;
  float I = a;
  float ds = d8;
#pragma unroll
  for (int s = 1; s < 64; s <<= 1) {
    float v = __shfl_up(I, s, 64);
    if (lane >= s) I += ds * v;
    ds *= ds;
  }
  if (lane == 63) wtot[wv] = I;
  __syncthreads();
  float carry = 0.f;
  for (int w2 = 0; w2 < wv; ++w2) carry = carry * ds + wtot[w2];
  float dlp1 = exp2f(log2f(d8) * (float)(lane + 1));
  float Ig = I + dlp1 * carry;
  float E = __shfl_up(Ig, 1, 64);
  if (lane == 0) E = carry;
  float S = E;
  float out[8];
#pragma unroll
  for (int i = 0; i < 8; ++i) {
    out[i] = S;
    S = d * (S + z[i]);
  }
  float4* wp = (float4*)(w + ((size_t)bh * 36 + ch) * 2048 + t0);
  wp[0] = make_float4(out[0], out[1], out[2], out[3]);
  wp[1] = make_float4(out[4], out[5], out[6], out[7]);
}

// ------------- scores[bh][t] = sum_ch r[p]*r[q] * w[bh][ch][t] ----------------------
__global__ __launch_bounds__(256) void k_scandot(const float* __restrict__ rr,
                                                 const float* __restrict__ w,
                                                 float* __restrict__ scores) {
  const int bh = blockIdx.y;
  const int t = blockIdx.x * 256 + threadIdx.x;
  const float* rb = rr + ((size_t)bh * 2048 + t) * 6;
  float r[6];
#pragma unroll
  for (int i = 0; i < 6; ++i) r[i] = rb[i];
  const float* wb = w + (size_t)bh * 36 * 2048 + t;
  float acc = 0.f;
#pragma unroll
  for (int ch = 0; ch < 36; ++ch)
    acc += r[ch / 6] * r[ch % 6] * wb[(size_t)ch * 2048];
  scores[(size_t)bh * 2048 + t] = acc;
}

// ---------------- gate: gmean[b,t] = mean_h sig(score*scale_h)*sig(memg) -----------
__global__ __launch_bounds__(256) void k_gate(const float* __restrict__ scores,
                                              const float* __restrict__ Cs,
                                              const float* __restrict__ memg_b,
                                              const float* __restrict__ mem_scale,
                                              float* __restrict__ gmean) {
  int idx = blockIdx.x * 256 + threadIdx.x;
  if (idx >= BT) return;
  int b = idx >> 11, t = idx & 2047;
  float acc = 0.f;
#pragma unroll
  for (int h = 0; h < 16; ++h) {
    float s = scores[((size_t)(b * 16 + h) * 2048) + t];
    float gl = Cs[(size_t)idx * 272 + 256 + h] + memg_b[h];
    float a = 1.f / (1.f + __expf(-s * mem_scale[h]));
    float gg = 1.f / (1.f + __expf(-gl));
    acc += a * gg;
  }
  gmean[idx] = acc * (1.f / 16.f);
}

// ---------------- fuse: Fb = bf16(seq_bf16 + gmean*memval_bf16) ----------------
__global__ __launch_bounds__(256) void k_fuse(const short* __restrict__ s,
                                              const short* __restrict__ mv,
                                              const float* __restrict__ gm,
                                              short* __restrict__ dst, int n4) {
  int i = blockIdx.x * 256 + threadIdx.x;
  if (i >= n4) return;
  float gg = gm[i >> 8];
  short4 a = ((const short4*)s)[i];
  short4 m = ((const short4*)mv)[i];
  short4 o;
  o.x = f2bf(bf2f(a.x) + gg * bf2f(m.x));
  o.y = f2bf(bf2f(a.y) + gg * bf2f(m.y));
  o.z = f2bf(bf2f(a.z) + gg * bf2f(m.z));
  o.w = f2bf(bf2f(a.w) + gg * bf2f(m.w));
  ((short4*)dst)[i] = o;
}

extern "C" void kernel_launch(void* const* d_in, const int* in_sizes, int n_in,
                              void* d_out, int out_size, void* d_ws, size_t ws_size,
                              hipStream_t stream) {
  const float* x = (const float*)d_in[0];
  const float* qkv_w = (const float*)d_in[1];
  const float* qkv_b = (const float*)d_in[2];
  const float* w1w = (const float*)d_in[3];
  const float* w2w = (const float*)d_in[4];
  const float* w1r = (const float*)d_in[5];
  const float* w2r = (const float*)d_in[6];
  const float* memv_w = (const float*)d_in[7];
  const float* memv_b = (const float*)d_in[8];
  const float* memg_w = (const float*)d_in[9];
  const float* memg_b = (const float*)d_in[10];
  const float* mem_scale = (const float*)d_in[11];
  const float* out_w = (const float*)d_in[12];
  const float* out_b = (const float*)d_in[13];
  const float* Jm = (const float*)d_in[14];
  const float* decays = (const float*)d_in[15];

  char* w = (char*)d_ws;
  size_t off = 0;
  auto alloc = [&](size_t bytes) -> void* {
    void* p = w + off;
    off += (bytes + 255) & ~(size_t)255;
    return p;
  };
  short* xb = (short*)alloc((size_t)BT * Dd * 2);            // 8MB   } p3
  short* WTall = (short*)alloc((size_t)4096 * 1024 * 2);     // 8MB   }
  short* WTsm = (short*)alloc((size_t)384 * 1024 * 2);
  short* WTout = (short*)alloc((size_t)1024 * 1024 * 2);
  short* qb = (short*)alloc((size_t)32 * 2048 * 64 * 2);     // 8MB   } p0
  short* kb = (short*)alloc((size_t)32 * 2048 * 64 * 2);     // 8MB   }
  short* vtmp = (short*)alloc((size_t)BT * 1024 * 2);        // 8MB   } p1
  short* vb = (short*)alloc((size_t)32 * 64 * 2048 * 2);     // 8MB   }
  float* Csm = (float*)alloc((size_t)BT * 272 * 4);
  float* ua = (float*)alloc((size_t)32 * 2048 * 6 * 4);
  float* ra = (float*)alloc((size_t)32 * 2048 * 6 * 4);
  float* sc = (float*)alloc((size_t)32 * 2048 * 4);
  float* gm = (float*)alloc((size_t)BT * 4);
  short* mvb = (short*)alloc((size_t)BT * 1024 * 2);         // 8MB   } p2
  short* seqo = (short*)alloc((size_t)BT * 1024 * 2);        // 8MB   }
  short* Fb = (short*)alloc((size_t)BT * Dd * 2);
  float* wscan = (float*)qb;  // aliases qb+kb, dead after k_scandot
  // split-K partials (16MB each), aliased onto buffer pairs dead by out-GEMM time:
  float* p0 = (float*)qb;    // qb+kb     (wscan also dead by then)
  float* p1 = (float*)vtmp;  // vtmp+vb
  float* p2 = (float*)mvb;   // mvb+seqo
  float* p3 = (float*)xb;    // xb+WTall
  (void)ws_size; (void)in_sizes; (void)n_in; (void)out_size;

  // prep
  k_cvt<<<(BT * Dd / 4 + 255) / 256, 256, 0, stream>>>(x, xb, BT * Dd / 4);
  k_wt2<<<dim3(48, 16), 256, 0, stream>>>(qkv_w, WTall, 1024, 3072);
  k_wt2<<<dim3(16, 16), 256, 0, stream>>>(memv_w, WTall + (size_t)3072 * 1024, 1024, 1024);
  k_wt5<<<dim3(1, 16, 5), 256, 0, stream>>>(w1w, w2w, w1r, w2r, memg_w, WTsm);
  k_wt2<<<dim3(16, 16), 256, 0, stream>>>(out_w, WTout, 1024, 1024);

  // fused 256^2 8-phase GEMM: qkv (3072) | memv (1024, ->bf16) over N=4096, grid=256
  k_g256<<<256, 512, 0, stream>>>(xb, WTall, qkv_b, memv_b,
                                  qb, kb, vtmp, mvb, 1024, 1);
  // sm projections (N=272, padded B to 384)
  k_gemm<<<dim3(3, 64), 256, 0, stream>>>(xb, WTsm, nullptr, Csm, 1024, 272, 272);

  k_vtrans<<<dim3(32, 32), 256, 0, stream>>>(vtmp, vb);

  // attention: 256 balanced blocks x 512 threads
  k_attn<<<256, 512, 0, stream>>>(qb, kb, vb, seqo);

  // memory path
  k_lines<<<(2 * 2048 * 16 + 255) / 256, 256, 0, stream>>>(Csm, Jm, ua, ra);
  k_scanw<<<dim3(36, 32), 256, 0, stream>>>(ua, wscan, decays);
  k_scandot<<<dim3(8, 32), 256, 0, stream>>>(ra, wscan, sc);
  k_gate<<<(BT + 255) / 256, 256, 0, stream>>>(sc, Csm, memg_b, mem_scale, gm);

  // fuse + final GEMM as split-K/4 over full chip (256 blocks) + reduce
  k_fuse<<<(BT * Dd / 4 + 255) / 256, 256, 0, stream>>>(seqo, mvb, gm, Fb, BT * Dd / 4);
  k_g256<<<256, 512, 0, stream>>>(Fb, WTout, nullptr, nullptr,
                                  (short*)p0, (short*)p1, (short*)p2, (short*)p3,
                                  1024, 2);
  k_red<<<BT * Dd / 4 / 256, 256, 0, stream>>>(p0, p1, p2, p3, out_b, (float*)d_out);
}